// Round 3
// baseline (915.995 us; speedup 1.0000x reference)
//
#include <hip/hip_runtime.h>
#include <hip/hip_bf16.h>

typedef unsigned short u16;
typedef unsigned int u32;
typedef __attribute__((ext_vector_type(8))) short short8;
typedef __attribute__((ext_vector_type(4))) float f32x4;

constexpr int SA     = 168;    // act row stride (bf16): 336 B
constexpr int BLK_E  = 64;     // edges per block
constexpr int NTHR   = 256;    // 4 waves = 2 M-groups x 2 N-groups (5/5 N-split)
constexpr int CHUNK  = 512;    // u16 elems per (ks,j) fragment chunk = 1 KB
constexpr int WSLOT  = 50 * CHUNK;              // 25600 elems per layer (5 ks x 10 j)
constexpr size_t WS_HDR   = 262144;             // weights header

// slice schedule: s=0 -> (L0,ks0); s=1..15 -> L1..L3 (5 ks each); s=16..20 -> L4
constexpr int Ls (int s) { return s == 0 ? 0 : (s <= 15 ? 1 + (s - 1) / 5 : 4); }
constexpr int Kss(int s) { return s == 0 ? 0 : (s <= 15 ? (s - 1) % 5 : s - 16); }

__device__ __forceinline__ u16 f2bf(float f) {  // RNE (prep only)
    union { float f; unsigned u; } c; c.f = f;
    return (u16)((c.u + 0x7fffu + ((c.u >> 16) & 1u)) >> 16);
}
__device__ __forceinline__ unsigned pk_bf16(float a, float b) {  // v_cvt_pk_bf16_f32
    float2 f; f.x = a; f.y = b;
    __hip_bfloat162 h = __float22bfloat162_rn(f);
    return *(unsigned*)&h;
}

// act k'-storage (5/5 N-split):
__device__ __forceinline__ int kperm(int kp) {
    if (kp < 64)  return (kp & 3) * 16 + (kp >> 2);
    if (kp < 128) { const int m = kp - 64; return (5 + (m & 3)) * 16 + (m >> 2); }
    if (kp < 144) return 4 * 16 + (kp - 128);
    if (kp < 160) return 9 * 16 + (kp - 144);
    return 1 << 30;
}

// ---- prep: weights -> fragment-ordered chunks, BIAS FOLDED IN --------------
__global__ void prep_all(const float* __restrict__ W0, const float* __restrict__ W1,
                         const float* __restrict__ W2, const float* __restrict__ W3,
                         const float* __restrict__ W4,
                         const float* __restrict__ B0, const float* __restrict__ B1,
                         const float* __restrict__ B2, const float* __restrict__ B3,
                         const float* __restrict__ B4,
                         u16* __restrict__ Wt)
{
    const int l = blockIdx.y;
    const float* W; const float* B; int DI, DO; bool perm;
    if      (l == 0) { W = W0; B = B0; DI = 13;  DO = 150; perm = false; }
    else if (l == 1) { W = W1; B = B1; DI = 150; DO = 150; perm = true;  }
    else if (l == 2) { W = W2; B = B2; DI = 150; DO = 150; perm = true;  }
    else if (l == 3) { W = W3; B = B3; DI = 150; DO = 150; perm = true;  }
    else             { W = W4; B = B4; DI = 150; DO = 50;  perm = true;  }
    const int kbias = (l == 0) ? 13 : 150;      // constant-1 input row
    u16* dst = Wt + (size_t)l * WSLOT;
    for (int idx = blockIdx.x * blockDim.x + threadIdx.x; idx < WSLOT;
         idx += gridDim.x * blockDim.x) {
        const int chunk = idx / CHUNK;            // = ks*10 + j
        const int within = idx - chunk * CHUNK;
        const int lane = within >> 3, e = within & 7;
        const int ks = chunk / 10, j = chunk - ks * 10;
        const int c = lane & 15, q = lane >> 4;
        const int n = j * 16 + c;
        const int kphys = ks * 32 + q * 8 + e;
        const int klog = perm ? kperm(kphys) : kphys;
        float v = 0.f;
        if (n < DO) {
            if (klog < DI)          v = W[klog * DO + n];
            else if (klog == kbias) v = B[n];     // folded bias row
        }
        dst[idx] = f2bf(v);
    }
}

// ---- B-load for slice s (plain global->VGPR, coalesced 1 KB chunks) --------
__device__ __forceinline__ void loadB(const u16* __restrict__ Wt, int s,
                                      int ng, int lane, short8 (&slot)[5])
{
    const int l = Ls(s), ks = Kss(s);
    const int jb = (l < 4) ? ng * 5 : 0;
    const int nt = (l < 4) ? 5 : 4;
    const u16* base = Wt + (size_t)l * WSLOT + (size_t)(ks * 10 + jb) * CHUNK + lane * 8;
#pragma unroll
    for (int jj = 0; jj < 5; ++jj)
        if (jj < nt) slot[jj] = *(const short8*)&base[jj * CHUNK];
}

// ---- epilogue: relu + packed bf16, k'-permuted in-place store --------------
__device__ __forceinline__ void epilogue(u16* act, int mg, int ng, int col, int quad,
                                         f32x4 (&acc)[2][5])
{
#pragma unroll
    for (int mtl = 0; mtl < 2; ++mtl)
#pragma unroll
        for (int r = 0; r < 4; ++r) {
            u16* row = &act[((mg * 2 + mtl) * 16 + quad * 4 + r) * SA];
            uint2 pk;
            pk.x = pk_bf16(fmaxf(acc[mtl][0][r], 0.f), fmaxf(acc[mtl][1][r], 0.f));
            pk.y = pk_bf16(fmaxf(acc[mtl][2][r], 0.f), fmaxf(acc[mtl][3][r], 0.f));
            *(uint2*)&row[ng * 64 + col * 4] = pk;                 // tiles 0-3 / 5-8
            u16 sv = (u16)pk_bf16(fmaxf(acc[mtl][4][r], 0.f), 0.f);
            if (ng == 1 && col == 6) sv = 0x3F80;                  // n=150 := 1.0
            row[128 + ng * 16 + col] = sv;                         // tile 4 / 9
        }
}

// ====================== counting sort of edges by tgt =======================
__global__ void hist_kernel(const int* __restrict__ tgt, u32* __restrict__ cnt,
                            int n_edges)
{
    const int e = blockIdx.x * blockDim.x + threadIdx.x;
    if (e < n_edges) atomicAdd(&cnt[tgt[e]], 1u);
}

// per-block exclusive scan (Hillis-Steele), 256 elems/block
__global__ void scan1_kernel(const u32* __restrict__ cnt, u32* __restrict__ offs,
                             u32* __restrict__ bsum, int n)
{
    __shared__ u32 s[256];
    const int i = blockIdx.x * 256 + threadIdx.x;
    const u32 v = (i < n) ? cnt[i] : 0u;
    s[threadIdx.x] = v; __syncthreads();
#pragma unroll
    for (int d = 1; d < 256; d <<= 1) {
        const u32 t = (threadIdx.x >= d) ? s[threadIdx.x - d] : 0u;
        __syncthreads();
        s[threadIdx.x] += t;
        __syncthreads();
    }
    if (i < n) offs[i] = s[threadIdx.x] - v;         // exclusive within block
    if (threadIdx.x == 255) bsum[blockIdx.x] = s[255];
}

__global__ void scan2_kernel(u32* __restrict__ bsum, int nb)   // nb <= 512
{
    __shared__ u32 s[512];
    const int i = threadIdx.x;
    const u32 v = (i < nb) ? bsum[i] : 0u;
    s[i] = v; __syncthreads();
#pragma unroll
    for (int d = 1; d < 512; d <<= 1) {
        const u32 t = (i >= d) ? s[i - d] : 0u;
        __syncthreads();
        s[i] += t;
        __syncthreads();
    }
    if (i < nb) bsum[i] = s[i] - v;                  // exclusive block bases
}

__global__ void scan3_kernel(u32* __restrict__ offs, const u32* __restrict__ bsum,
                             u32* __restrict__ cursor, int n, int n_edges)
{
    const int i = blockIdx.x * 256 + threadIdx.x;
    if (i < n) {
        const u32 o = offs[i] + bsum[blockIdx.x];
        offs[i] = o;
        cursor[i] = o;
    }
    if (blockIdx.x == 0 && threadIdx.x == 0) offs[n] = (u32)n_edges;
}

// single int2 scatter per edge (one 8B transaction instead of two 4B)
__global__ void perm_kernel(const int* __restrict__ src, const int* __restrict__ tgt,
                            u32* __restrict__ cursor, int2* __restrict__ sg,
                            int n_edges)
{
    const int e = blockIdx.x * blockDim.x + threadIdx.x;
    if (e < n_edges) {
        const int g = tgt[e];
        const u32 pos = atomicAdd(&cursor[g], 1u);
        sg[pos] = make_int2(src[e], g);
    }
}

// ------------------------------- Edge kernel --------------------------------
// Edges SORTED BY TGT. 2-deep B register window (-20 VGPR vs 3-deep) +
// launch_bounds min-waves 5 => target 5 waves/SIMD (was ~3.5).
__global__ __launch_bounds__(NTHR, 5) void edge_kernel(
    const float* __restrict__ t, const float* __restrict__ x, const float* __restrict__ Ofx,
    const int2* __restrict__ sgp,
    const u16* __restrict__ Wt,
    float* __restrict__ Ep, int n_edges)
{
    __shared__ __align__(16) u16 act[BLK_E * SA];      // 21504 B (reused as f32 E-tile)
    __shared__ int tgt_s[BLK_E];                       // 256 B

    const int tid  = threadIdx.x;
    const int lane = tid & 63;
    const int wv   = tid >> 6;
    const int mg   = wv >> 1;          // M-group: edges [mg*32, mg*32+32)
    const int ng   = wv & 1;           // N-group: tiles [ng*5, ng*5+5)
    const int col  = lane & 15;
    const int quad = lane >> 4;

    short8 Bwin[2][5];
    loadB(Wt, 0, ng, lane, Bwin[0]);    // prologue: 2-deep lookahead
    loadB(Wt, 1, ng, lane, Bwin[1]);

    // ---- gather R': each wave loads 16 edges (lanes 0-15) ------------------
    if (lane < 16) {
        const int e = wv * 16 + lane;
        const long long ge = (long long)blockIdx.x * BLK_E + e;
        const bool valid = ge < n_edges;
        const int2 sg = valid ? sgp[ge] : make_int2(0, 0);
        const int s = sg.x;
        const int g = valid ? sg.y : -1;
        const float4 xs = valid ? *(const float4*)&x[(size_t)s * 4] : float4{0, 0, 0, 0};
        const float2 os = valid ? *(const float2*)&Ofx[(size_t)s * 2] : float2{0, 0};
        const float4 xg = valid ? *(const float4*)&x[(size_t)sg.y * 4] : float4{0, 0, 0, 0};
        const float2 og = valid ? *(const float2*)&Ofx[(size_t)sg.y * 2] : float2{0, 0};
        const float tv = valid ? t[0] : 0.f;
        uint4 w0, w1;
        w0.x = pk_bf16(xs.x, xs.y); w0.y = pk_bf16(xs.z, xs.w);
        w0.z = pk_bf16(os.x, os.y); w0.w = pk_bf16(xg.x, xg.y);
        w1.x = pk_bf16(xg.z, xg.w); w1.y = pk_bf16(og.x, og.y);
        w1.z = pk_bf16(tv, 1.0f);   w1.w = 0u;     // k=13 := 1 (bias neuron)
        u16* row = &act[e * SA];
        *(uint4*)&row[0]  = w0;
        *(uint4*)&row[8]  = w1;
        *(uint4*)&row[16] = uint4{0, 0, 0, 0};
        *(uint4*)&row[24] = uint4{0, 0, 0, 0};
        tgt_s[e] = g;
    }
    __syncthreads();

    const f32x4 z = {0.f, 0.f, 0.f, 0.f};
    f32x4 acc[2][5];
    short8 Af[2];

    // ---- s=0: L0 (K=32), C = 0 inline ----
#pragma unroll
    for (int mtl = 0; mtl < 2; ++mtl)
        Af[mtl] = *(const short8*)&act[((mg * 2 + mtl) * 16 + col) * SA + quad * 8];
#pragma unroll
    for (int jj = 0; jj < 5; ++jj)
#pragma unroll
        for (int mtl = 0; mtl < 2; ++mtl)
            acc[mtl][jj] = __builtin_amdgcn_mfma_f32_16x16x32_bf16(
                Af[mtl], Bwin[0][jj], z, 0, 0, 0);
    loadB(Wt, 2, ng, lane, Bwin[0]);       // refill slot 0 (s=2)
    __syncthreads();                        // A-reads done
    epilogue(act, mg, ng, col, quad, acc);
    __syncthreads();                        // epilogue visible

    // ---- s=1..15: L1..L3 ----
#pragma unroll
    for (int s = 1; s <= 15; ++s) {
        const int ks = (s - 1) % 5;
        const int slot = s & 1;
#pragma unroll
        for (int mtl = 0; mtl < 2; ++mtl)
            Af[mtl] = *(const short8*)&act[((mg * 2 + mtl) * 16 + col) * SA
                                           + ks * 32 + quad * 8];
#pragma unroll
        for (int jj = 0; jj < 5; ++jj)
#pragma unroll
            for (int mtl = 0; mtl < 2; ++mtl) {
                if (ks == 0)
                    acc[mtl][jj] = __builtin_amdgcn_mfma_f32_16x16x32_bf16(
                        Af[mtl], Bwin[slot][jj], z, 0, 0, 0);
                else
                    acc[mtl][jj] = __builtin_amdgcn_mfma_f32_16x16x32_bf16(
                        Af[mtl], Bwin[slot][jj], acc[mtl][jj], 0, 0, 0);
            }
        if (s + 2 <= 20) loadB(Wt, s + 2, ng, lane, Bwin[slot]);
        if (ks == 4) {
            __syncthreads();                // all A-reads of layer done
            epilogue(act, mg, ng, col, quad, acc);
            __syncthreads();                // epilogue visible
        }
    }

    // ---- s=16..20: L4 — one M-tile per wave (mt = 2mg+ng), full N=4 --------
    const int mt4 = mg * 2 + ng;
    f32x4 acc4[4];
#pragma unroll
    for (int s = 16; s <= 20; ++s) {
        const int ks = s - 16;
        const int slot = s & 1;
        const short8 A4 = *(const short8*)&act[(mt4 * 16 + col) * SA
                                               + ks * 32 + quad * 8];
#pragma unroll
        for (int jj = 0; jj < 4; ++jj) {
            if (ks == 0)
                acc4[jj] = __builtin_amdgcn_mfma_f32_16x16x32_bf16(
                    A4, Bwin[slot][jj], z, 0, 0, 0);
            else
                acc4[jj] = __builtin_amdgcn_mfma_f32_16x16x32_bf16(
                    A4, Bwin[slot][jj], acc4[jj], 0, 0, 0);
        }
        if (s + 2 <= 20) loadB(Wt, s + 2, ng, lane, Bwin[slot]);  // refill 19,20
    }

    // ---- segment-reduced scatter (edges sorted by tgt) ---------------------
    __syncthreads();                        // all L4 A-reads of act done
    float* actF = (float*)act;              // reuse act LDS as f32 [64][52]
#pragma unroll
    for (int jj = 0; jj < 4; ++jj) {
        const int n = jj * 16 + col;
        if (n < 50) {
#pragma unroll
            for (int r = 0; r < 4; ++r)
                actF[(mt4 * 16 + quad * 4 + r) * 52 + n] = acc4[jj][r];
        }
    }
    __syncthreads();                        // E tile visible
    // 200 threads: (quarter h, col c). Scan 16 sorted rows, one atomic per run
    // segment within the quarter (runs crossing quarters -> extra atomic, OK).
    if (tid < 200) {
        const int h = tid / 50;
        const int c = tid - h * 50;
        const int r0 = h * 16;
        int   cur = tgt_s[r0];
        float a   = 0.f;
        for (int r = r0; r < r0 + 16; ++r) {
            const int   g = tgt_s[r];
            const float v = actF[r * 52 + c];
            if (g != cur) {
                if (cur >= 0) atomicAdd(&Ep[(size_t)cur * 50 + c], a);
                a = 0.f; cur = g;
            }
            a += v;
        }
        if (cur >= 0) atomicAdd(&Ep[(size_t)cur * 50 + c], a);
    }
}

// ---------------- Node kernel: fO MLP (fp32 VALU) ---------------------------
template<int DI, int DO, bool RELU>
__device__ __forceinline__ void mlp_layer_t(
    const float* __restrict__ W, const float* __restrict__ B,
    float (*in)[64], float (*out)[64], int tid)
{
    const int et = tid & 15;
    const int jt = tid >> 4;
    constexpr int NG = (DO + 15) / 16;

    float acc0[NG], acc1[NG], acc2[NG], acc3[NG];
#pragma unroll
    for (int g = 0; g < NG; ++g) {
        const int j = jt + 16 * g;
        const float bb = (j < DO) ? B[j] : 0.f;
        acc0[g] = bb; acc1[g] = bb; acc2[g] = bb; acc3[g] = bb;
    }
    for (int k = 0; k < DI; ++k) {
        const float4 a = *(const float4*)&in[k][et * 4];
#pragma unroll
        for (int g = 0; g < NG; ++g) {
            const int j = jt + 16 * g;
            const float wv = (j < DO) ? W[k * DO + j] : 0.f;
            acc0[g] = fmaf(a.x, wv, acc0[g]);
            acc1[g] = fmaf(a.y, wv, acc1[g]);
            acc2[g] = fmaf(a.z, wv, acc2[g]);
            acc3[g] = fmaf(a.w, wv, acc3[g]);
        }
    }
#pragma unroll
    for (int g = 0; g < NG; ++g) {
        const int j = jt + 16 * g;
        if (j < DO) {
            float4 v; v.x = acc0[g]; v.y = acc1[g]; v.z = acc2[g]; v.w = acc3[g];
            if (RELU) {
                v.x = fmaxf(v.x, 0.f); v.y = fmaxf(v.y, 0.f);
                v.z = fmaxf(v.z, 0.f); v.w = fmaxf(v.w, 0.f);
            }
            *(float4*)&out[j][et * 4] = v;
        }
    }
}

__global__ __launch_bounds__(256, 3) void node_kernel(
    const float* __restrict__ Ep,
    const float* __restrict__ W0, const float* __restrict__ B0,
    const float* __restrict__ W1, const float* __restrict__ B1,
    float* __restrict__ P, int n_nodes)
{
    __shared__ float bufA[104][64];
    __shared__ float bufB[104][64];
    const int tid = threadIdx.x;
    const int n0  = blockIdx.x * 64;

    for (int idx = tid; idx < 64 * 50; idx += 256) {
        const int e = idx / 50;
        const int k = idx - e * 50;
        const int n = n0 + e;
        bufA[k][e] = (n < n_nodes) ? Ep[(size_t)n * 50 + k] : 0.f;
    }
    __syncthreads();
    mlp_layer_t<50, 100, true >(W0, B0, bufA, bufB, tid); __syncthreads();
    mlp_layer_t<100, 4, false>(W1, B1, bufB, bufA, tid); __syncthreads();
    for (int idx = tid; idx < 64 * 4; idx += 256) {
        const int e = idx & 63;
        const int j = idx >> 6;
        const int n = n0 + e;
        if (n < n_nodes) P[(size_t)n * 4 + j] = bufA[j][e];
    }
}

// ------------------------------- launcher -----------------------------------
extern "C" void kernel_launch(void* const* d_in, const int* in_sizes, int n_in,
                              void* d_out, int out_size, void* d_ws, size_t ws_size,
                              hipStream_t stream)
{
    const float* t   = (const float*)d_in[0];
    const float* x   = (const float*)d_in[1];
    const float* Ofx = (const float*)d_in[2];
    const int*   src = (const int*)d_in[3];
    const int*   tgt = (const int*)d_in[4];
    const float* W0  = (const float*)d_in[5];  const float* B0 = (const float*)d_in[6];
    const float* W1  = (const float*)d_in[7];  const float* B1 = (const float*)d_in[8];
    const float* W2  = (const float*)d_in[9];  const float* B2 = (const float*)d_in[10];
    const float* W3  = (const float*)d_in[11]; const float* B3 = (const float*)d_in[12];
    const float* W4  = (const float*)d_in[13]; const float* B4 = (const float*)d_in[14];
    const float* OW0 = (const float*)d_in[15]; const float* OB0 = (const float*)d_in[16];
    const float* OW1 = (const float*)d_in[17]; const float* OB1 = (const float*)d_in[18];

    const int n_nodes = in_sizes[1] / 4;
    const int n_edges = in_sizes[3];

    // workspace layout (all 256-B aligned)
    auto align256 = [](size_t v) { return (v + 255) & ~(size_t)255; };
    char* ws = (char*)d_ws;
    const size_t copy_elems = (size_t)n_nodes * 50;
    size_t o = 0;
    u16*   Wt       = (u16*)(ws + o);  o = WS_HDR;
    float* Ep       = (float*)(ws + o); o = align256(o + copy_elems * sizeof(float));
    u32*   offs     = (u32*)(ws + o);  o = align256(o + (size_t)(n_nodes + 1) * 4);
    u32*   cursor   = (u32*)(ws + o);  o = align256(o + (size_t)n_nodes * 4);  // also hist cnt
    u32*   bsum     = (u32*)(ws + o);  o = align256(o + 512 * 4);
    int2*  sg_perm  = (int2*)(ws + o); o = align256(o + (size_t)n_edges * 8);

    const int NB  = (n_nodes + 255) / 256;          // 391 for 100K (scan2 handles <=512)
    const int EBK = (n_edges + 255) / 256;

    prep_all<<<dim3(32, 5), 256, 0, stream>>>(W0, W1, W2, W3, W4,
                                              B0, B1, B2, B3, B4, Wt);
    hipMemsetAsync(Ep, 0, copy_elems * sizeof(float), stream);
    hipMemsetAsync(cursor, 0, (size_t)n_nodes * 4, stream);

    // counting sort of edges by tgt
    hist_kernel <<<EBK, 256, 0, stream>>>(tgt, cursor, n_edges);
    scan1_kernel<<<NB, 256, 0, stream>>>(cursor, offs, bsum, n_nodes);
    scan2_kernel<<<1, 512, 0, stream>>>(bsum, NB);
    scan3_kernel<<<NB, 256, 0, stream>>>(offs, bsum, cursor, n_nodes, n_edges);
    perm_kernel <<<EBK, 256, 0, stream>>>(src, tgt, cursor, sg_perm, n_edges);

    edge_kernel<<<(n_edges + BLK_E - 1) / BLK_E, NTHR, 0, stream>>>(
        t, x, Ofx, sg_perm, Wt, Ep, n_edges);

    node_kernel<<<(n_nodes + 63) / 64, 256, 0, stream>>>(
        Ep, OW0, OB0, OW1, OB1, (float*)d_out, n_nodes);
}

// Round 4
// 907.216 us; speedup vs baseline: 1.0097x; 1.0097x over previous
//
#include <hip/hip_runtime.h>
#include <hip/hip_bf16.h>

typedef unsigned short u16;
typedef unsigned int u32;
typedef __attribute__((ext_vector_type(8))) short short8;
typedef __attribute__((ext_vector_type(4))) float f32x4;

constexpr int SA     = 192;    // act row stride (bf16): 384 B (96 dw, bank-neutral)
constexpr int BLK_E  = 64;     // edges per block
constexpr int NTHR   = 256;    // 4 waves = 2 M-groups x 2 N-groups (5/5 N-split)
constexpr int CHUNK  = 512;    // u16 elems per (ks,j) fragment chunk = 1 KB
constexpr int WSLOT  = 50 * CHUNK;              // 25600 elems per layer (5 ks x 10 j)
constexpr size_t WS_HDR   = 262144;             // weights header

// slice schedule: s=0 -> (L0,ks0); s=1..15 -> L1..L3 (5 ks each); s=16..20 -> L4
constexpr int Ls (int s) { return s == 0 ? 0 : (s <= 15 ? 1 + (s - 1) / 5 : 4); }
constexpr int Kss(int s) { return s == 0 ? 0 : (s <= 15 ? (s - 1) % 5 : s - 16); }

// act XOR-swizzle: 16B-block index ^= (row&7). With SA=192 (96 dw, 96%32==0)
// the row base contributes no bank bits, so the XOR fully spreads the 8-bank
// coset that SA=168 suffered (84 dw, gcd 4 -> 8 banks, 4x beats on A-reads).
// Writer and reader MUST both use aswz (both-sides-or-neither).
__device__ __forceinline__ int aswz(int row, int elem) {
    return row * SA + (elem ^ ((row & 7) << 3));
}

__device__ __forceinline__ u16 f2bf(float f) {  // RNE (prep only)
    union { float f; unsigned u; } c; c.f = f;
    return (u16)((c.u + 0x7fffu + ((c.u >> 16) & 1u)) >> 16);
}
__device__ __forceinline__ unsigned pk_bf16(float a, float b) {  // v_cvt_pk_bf16_f32
    float2 f; f.x = a; f.y = b;
    __hip_bfloat162 h = __float22bfloat162_rn(f);
    return *(unsigned*)&h;
}

// act k'-storage (5/5 N-split):
__device__ __forceinline__ int kperm(int kp) {
    if (kp < 64)  return (kp & 3) * 16 + (kp >> 2);
    if (kp < 128) { const int m = kp - 64; return (5 + (m & 3)) * 16 + (m >> 2); }
    if (kp < 144) return 4 * 16 + (kp - 128);
    if (kp < 160) return 9 * 16 + (kp - 144);
    return 1 << 30;
}

// ---- prep: weights -> fragment-ordered chunks, BIAS FOLDED IN --------------
__global__ void prep_all(const float* __restrict__ W0, const float* __restrict__ W1,
                         const float* __restrict__ W2, const float* __restrict__ W3,
                         const float* __restrict__ W4,
                         const float* __restrict__ B0, const float* __restrict__ B1,
                         const float* __restrict__ B2, const float* __restrict__ B3,
                         const float* __restrict__ B4,
                         u16* __restrict__ Wt)
{
    const int l = blockIdx.y;
    const float* W; const float* B; int DI, DO; bool perm;
    if      (l == 0) { W = W0; B = B0; DI = 13;  DO = 150; perm = false; }
    else if (l == 1) { W = W1; B = B1; DI = 150; DO = 150; perm = true;  }
    else if (l == 2) { W = W2; B = B2; DI = 150; DO = 150; perm = true;  }
    else if (l == 3) { W = W3; B = B3; DI = 150; DO = 150; perm = true;  }
    else             { W = W4; B = B4; DI = 150; DO = 50;  perm = true;  }
    const int kbias = (l == 0) ? 13 : 150;      // constant-1 input row
    u16* dst = Wt + (size_t)l * WSLOT;
    for (int idx = blockIdx.x * blockDim.x + threadIdx.x; idx < WSLOT;
         idx += gridDim.x * blockDim.x) {
        const int chunk = idx / CHUNK;            // = ks*10 + j
        const int within = idx - chunk * CHUNK;
        const int lane = within >> 3, e = within & 7;
        const int ks = chunk / 10, j = chunk - ks * 10;
        const int c = lane & 15, q = lane >> 4;
        const int n = j * 16 + c;
        const int kphys = ks * 32 + q * 8 + e;
        const int klog = perm ? kperm(kphys) : kphys;
        float v = 0.f;
        if (n < DO) {
            if (klog < DI)          v = W[klog * DO + n];
            else if (klog == kbias) v = B[n];     // folded bias row
        }
        dst[idx] = f2bf(v);
    }
}

// ---- B-load for slice s (plain global->VGPR, coalesced 1 KB chunks) --------
__device__ __forceinline__ void loadB(const u16* __restrict__ Wt, int s,
                                      int ng, int lane, short8 (&slot)[5])
{
    const int l = Ls(s), ks = Kss(s);
    const int jb = (l < 4) ? ng * 5 : 0;
    const int nt = (l < 4) ? 5 : 4;
    const u16* base = Wt + (size_t)l * WSLOT + (size_t)(ks * 10 + jb) * CHUNK + lane * 8;
#pragma unroll
    for (int jj = 0; jj < 5; ++jj)
        if (jj < nt) slot[jj] = *(const short8*)&base[jj * CHUNK];
}

// ---- epilogue: relu + packed bf16, k'-permuted swizzled store --------------
__device__ __forceinline__ void epilogue(u16* act, int mg, int ng, int col, int quad,
                                         f32x4 (&acc)[2][5])
{
#pragma unroll
    for (int mtl = 0; mtl < 2; ++mtl)
#pragma unroll
        for (int r = 0; r < 4; ++r) {
            const int row = (mg * 2 + mtl) * 16 + quad * 4 + r;
            uint2 pk;
            pk.x = pk_bf16(fmaxf(acc[mtl][0][r], 0.f), fmaxf(acc[mtl][1][r], 0.f));
            pk.y = pk_bf16(fmaxf(acc[mtl][2][r], 0.f), fmaxf(acc[mtl][3][r], 0.f));
            *(uint2*)&act[aswz(row, ng * 64 + col * 4)] = pk;      // tiles 0-3 / 5-8
            u16 sv = (u16)pk_bf16(fmaxf(acc[mtl][4][r], 0.f), 0.f);
            if (ng == 1 && col == 6) sv = 0x3F80;                  // n=150 := 1.0
            act[aswz(row, 128 + ng * 16 + col)] = sv;              // tile 4 / 9
        }
}

// ====================== counting sort of edges by tgt =======================
__global__ void hist_kernel(const int* __restrict__ tgt, u32* __restrict__ cnt,
                            int n_edges)
{
    const int e = blockIdx.x * blockDim.x + threadIdx.x;
    if (e < n_edges) atomicAdd(&cnt[tgt[e]], 1u);
}

// per-block exclusive scan (Hillis-Steele), 256 elems/block
__global__ void scan1_kernel(const u32* __restrict__ cnt, u32* __restrict__ offs,
                             u32* __restrict__ bsum, int n)
{
    __shared__ u32 s[256];
    const int i = blockIdx.x * 256 + threadIdx.x;
    const u32 v = (i < n) ? cnt[i] : 0u;
    s[threadIdx.x] = v; __syncthreads();
#pragma unroll
    for (int d = 1; d < 256; d <<= 1) {
        const u32 t = (threadIdx.x >= d) ? s[threadIdx.x - d] : 0u;
        __syncthreads();
        s[threadIdx.x] += t;
        __syncthreads();
    }
    if (i < n) offs[i] = s[threadIdx.x] - v;         // exclusive within block
    if (threadIdx.x == 255) bsum[blockIdx.x] = s[255];
}

__global__ void scan2_kernel(u32* __restrict__ bsum, int nb)   // nb <= 512
{
    __shared__ u32 s[512];
    const int i = threadIdx.x;
    const u32 v = (i < nb) ? bsum[i] : 0u;
    s[i] = v; __syncthreads();
#pragma unroll
    for (int d = 1; d < 512; d <<= 1) {
        const u32 t = (i >= d) ? s[i - d] : 0u;
        __syncthreads();
        s[i] += t;
        __syncthreads();
    }
    if (i < nb) bsum[i] = s[i] - v;                  // exclusive block bases
}

__global__ void scan3_kernel(u32* __restrict__ offs, const u32* __restrict__ bsum,
                             u32* __restrict__ cursor, int n, int n_edges)
{
    const int i = blockIdx.x * 256 + threadIdx.x;
    if (i < n) {
        const u32 o = offs[i] + bsum[blockIdx.x];
        offs[i] = o;
        cursor[i] = o;
    }
    if (blockIdx.x == 0 && threadIdx.x == 0) offs[n] = (u32)n_edges;
}

// single int2 scatter per edge (one 8B transaction instead of two 4B)
__global__ void perm_kernel(const int* __restrict__ src, const int* __restrict__ tgt,
                            u32* __restrict__ cursor, int2* __restrict__ sg,
                            int n_edges)
{
    const int e = blockIdx.x * blockDim.x + threadIdx.x;
    if (e < n_edges) {
        const int g = tgt[e];
        const u32 pos = atomicAdd(&cursor[g], 1u);
        sg[pos] = make_int2(src[e], g);
    }
}

// ------------------------------- Edge kernel --------------------------------
// Edges SORTED BY TGT. act rows XOR-swizzled (SA=192) -> conflict-free A-reads.
__global__ __launch_bounds__(NTHR, 4) void edge_kernel(
    const float* __restrict__ t, const float* __restrict__ x, const float* __restrict__ Ofx,
    const int2* __restrict__ sgp,
    const u16* __restrict__ Wt,
    float* __restrict__ Ep, int n_edges)
{
    __shared__ __align__(16) u16 act[BLK_E * SA];      // 24576 B (reused as f32 E-tile)
    __shared__ int tgt_s[BLK_E];                       // 256 B

    const int tid  = threadIdx.x;
    const int lane = tid & 63;
    const int wv   = tid >> 6;
    const int mg   = wv >> 1;          // M-group: edges [mg*32, mg*32+32)
    const int ng   = wv & 1;           // N-group: tiles [ng*5, ng*5+5)
    const int col  = lane & 15;
    const int quad = lane >> 4;

    short8 Bwin[2][5];
    loadB(Wt, 0, ng, lane, Bwin[0]);    // prologue: 2-deep lookahead
    loadB(Wt, 1, ng, lane, Bwin[1]);

    // ---- gather R': each wave loads 16 edges (lanes 0-15) ------------------
    if (lane < 16) {
        const int e = wv * 16 + lane;
        const long long ge = (long long)blockIdx.x * BLK_E + e;
        const bool valid = ge < n_edges;
        const int2 sg = valid ? sgp[ge] : make_int2(0, 0);
        const int s = sg.x;
        const int g = valid ? sg.y : -1;
        const float4 xs = valid ? *(const float4*)&x[(size_t)s * 4] : float4{0, 0, 0, 0};
        const float2 os = valid ? *(const float2*)&Ofx[(size_t)s * 2] : float2{0, 0};
        const float4 xg = valid ? *(const float4*)&x[(size_t)sg.y * 4] : float4{0, 0, 0, 0};
        const float2 og = valid ? *(const float2*)&Ofx[(size_t)sg.y * 2] : float2{0, 0};
        const float tv = valid ? t[0] : 0.f;
        uint4 w0, w1;
        w0.x = pk_bf16(xs.x, xs.y); w0.y = pk_bf16(xs.z, xs.w);
        w0.z = pk_bf16(os.x, os.y); w0.w = pk_bf16(xg.x, xg.y);
        w1.x = pk_bf16(xg.z, xg.w); w1.y = pk_bf16(og.x, og.y);
        w1.z = pk_bf16(tv, 1.0f);   w1.w = 0u;     // k=13 := 1 (bias neuron)
        *(uint4*)&act[aswz(e, 0)]  = w0;
        *(uint4*)&act[aswz(e, 8)]  = w1;
        *(uint4*)&act[aswz(e, 16)] = uint4{0, 0, 0, 0};
        *(uint4*)&act[aswz(e, 24)] = uint4{0, 0, 0, 0};
        tgt_s[e] = g;
    }
    __syncthreads();

    const f32x4 z = {0.f, 0.f, 0.f, 0.f};
    f32x4 acc[2][5];
    short8 Af[2];

    // ---- s=0: L0 (K=32), C = 0 inline ----
#pragma unroll
    for (int mtl = 0; mtl < 2; ++mtl)
        Af[mtl] = *(const short8*)&act[aswz((mg * 2 + mtl) * 16 + col, quad * 8)];
#pragma unroll
    for (int jj = 0; jj < 5; ++jj)
#pragma unroll
        for (int mtl = 0; mtl < 2; ++mtl)
            acc[mtl][jj] = __builtin_amdgcn_mfma_f32_16x16x32_bf16(
                Af[mtl], Bwin[0][jj], z, 0, 0, 0);
    loadB(Wt, 2, ng, lane, Bwin[0]);       // refill slot 0 (s=2)
    __syncthreads();                        // A-reads done
    epilogue(act, mg, ng, col, quad, acc);
    __syncthreads();                        // epilogue visible

    // ---- s=1..15: L1..L3 ----
#pragma unroll
    for (int s = 1; s <= 15; ++s) {
        const int ks = (s - 1) % 5;
        const int slot = s & 1;
#pragma unroll
        for (int mtl = 0; mtl < 2; ++mtl)
            Af[mtl] = *(const short8*)&act[aswz((mg * 2 + mtl) * 16 + col,
                                                ks * 32 + quad * 8)];
#pragma unroll
        for (int jj = 0; jj < 5; ++jj)
#pragma unroll
            for (int mtl = 0; mtl < 2; ++mtl) {
                if (ks == 0)
                    acc[mtl][jj] = __builtin_amdgcn_mfma_f32_16x16x32_bf16(
                        Af[mtl], Bwin[slot][jj], z, 0, 0, 0);
                else
                    acc[mtl][jj] = __builtin_amdgcn_mfma_f32_16x16x32_bf16(
                        Af[mtl], Bwin[slot][jj], acc[mtl][jj], 0, 0, 0);
            }
        if (s + 2 <= 20) loadB(Wt, s + 2, ng, lane, Bwin[slot]);
        if (ks == 4) {
            __syncthreads();                // all A-reads of layer done
            epilogue(act, mg, ng, col, quad, acc);
            __syncthreads();                // epilogue visible
        }
    }

    // ---- s=16..20: L4 — one M-tile per wave (mt = 2mg+ng), full N=4 --------
    const int mt4 = mg * 2 + ng;
    f32x4 acc4[4];
#pragma unroll
    for (int s = 16; s <= 20; ++s) {
        const int ks = s - 16;
        const int slot = s & 1;
        const short8 A4 = *(const short8*)&act[aswz(mt4 * 16 + col,
                                                    ks * 32 + quad * 8)];
#pragma unroll
        for (int jj = 0; jj < 4; ++jj) {
            if (ks == 0)
                acc4[jj] = __builtin_amdgcn_mfma_f32_16x16x32_bf16(
                    A4, Bwin[slot][jj], z, 0, 0, 0);
            else
                acc4[jj] = __builtin_amdgcn_mfma_f32_16x16x32_bf16(
                    A4, Bwin[slot][jj], acc4[jj], 0, 0, 0);
        }
        if (s + 2 <= 20) loadB(Wt, s + 2, ng, lane, Bwin[slot]);  // refill 19,20
    }

    // ---- segment-reduced scatter (edges sorted by tgt) ---------------------
    __syncthreads();                        // all L4 A-reads of act done
    float* actF = (float*)act;              // reuse act LDS as f32 [64][52] (no swz)
#pragma unroll
    for (int jj = 0; jj < 4; ++jj) {
        const int n = jj * 16 + col;
        if (n < 50) {
#pragma unroll
            for (int r = 0; r < 4; ++r)
                actF[(mt4 * 16 + quad * 4 + r) * 52 + n] = acc4[jj][r];
        }
    }
    __syncthreads();                        // E tile visible
    // 200 threads: (quarter h, col c). Scan 16 sorted rows, one atomic per run
    // segment within the quarter (runs crossing quarters -> extra atomic, OK).
    if (tid < 200) {
        const int h = tid / 50;
        const int c = tid - h * 50;
        const int r0 = h * 16;
        int   cur = tgt_s[r0];
        float a   = 0.f;
        for (int r = r0; r < r0 + 16; ++r) {
            const int   g = tgt_s[r];
            const float v = actF[r * 52 + c];
            if (g != cur) {
                if (cur >= 0) atomicAdd(&Ep[(size_t)cur * 50 + c], a);
                a = 0.f; cur = g;
            }
            a += v;
        }
        if (cur >= 0) atomicAdd(&Ep[(size_t)cur * 50 + c], a);
    }
}

// ---------------- Node kernel: fO MLP (fp32 VALU) ---------------------------
template<int DI, int DO, bool RELU>
__device__ __forceinline__ void mlp_layer_t(
    const float* __restrict__ W, const float* __restrict__ B,
    float (*in)[64], float (*out)[64], int tid)
{
    const int et = tid & 15;
    const int jt = tid >> 4;
    constexpr int NG = (DO + 15) / 16;

    float acc0[NG], acc1[NG], acc2[NG], acc3[NG];
#pragma unroll
    for (int g = 0; g < NG; ++g) {
        const int j = jt + 16 * g;
        const float bb = (j < DO) ? B[j] : 0.f;
        acc0[g] = bb; acc1[g] = bb; acc2[g] = bb; acc3[g] = bb;
    }
    for (int k = 0; k < DI; ++k) {
        const float4 a = *(const float4*)&in[k][et * 4];
#pragma unroll
        for (int g = 0; g < NG; ++g) {
            const int j = jt + 16 * g;
            const float wv = (j < DO) ? W[k * DO + j] : 0.f;
            acc0[g] = fmaf(a.x, wv, acc0[g]);
            acc1[g] = fmaf(a.y, wv, acc1[g]);
            acc2[g] = fmaf(a.z, wv, acc2[g]);
            acc3[g] = fmaf(a.w, wv, acc3[g]);
        }
    }
#pragma unroll
    for (int g = 0; g < NG; ++g) {
        const int j = jt + 16 * g;
        if (j < DO) {
            float4 v; v.x = acc0[g]; v.y = acc1[g]; v.z = acc2[g]; v.w = acc3[g];
            if (RELU) {
                v.x = fmaxf(v.x, 0.f); v.y = fmaxf(v.y, 0.f);
                v.z = fmaxf(v.z, 0.f); v.w = fmaxf(v.w, 0.f);
            }
            *(float4*)&out[j][et * 4] = v;
        }
    }
}

__global__ __launch_bounds__(256, 2) void node_kernel(
    const float* __restrict__ Ep,
    const float* __restrict__ W0, const float* __restrict__ B0,
    const float* __restrict__ W1, const float* __restrict__ B1,
    float* __restrict__ P, int n_nodes)
{
    __shared__ float bufA[104][64];
    __shared__ float bufB[104][64];
    const int tid = threadIdx.x;
    const int n0  = blockIdx.x * 64;

    for (int idx = tid; idx < 64 * 50; idx += 256) {
        const int e = idx / 50;
        const int k = idx - e * 50;
        const int n = n0 + e;
        bufA[k][e] = (n < n_nodes) ? Ep[(size_t)n * 50 + k] : 0.f;
    }
    __syncthreads();
    mlp_layer_t<50, 100, true >(W0, B0, bufA, bufB, tid); __syncthreads();
    mlp_layer_t<100, 4, false>(W1, B1, bufB, bufA, tid); __syncthreads();
    for (int idx = tid; idx < 64 * 4; idx += 256) {
        const int e = idx & 63;
        const int j = idx >> 6;
        const int n = n0 + e;
        if (n < n_nodes) P[(size_t)n * 4 + j] = bufA[j][e];
    }
}

// ------------------------------- launcher -----------------------------------
extern "C" void kernel_launch(void* const* d_in, const int* in_sizes, int n_in,
                              void* d_out, int out_size, void* d_ws, size_t ws_size,
                              hipStream_t stream)
{
    const float* t   = (const float*)d_in[0];
    const float* x   = (const float*)d_in[1];
    const float* Ofx = (const float*)d_in[2];
    const int*   src = (const int*)d_in[3];
    const int*   tgt = (const int*)d_in[4];
    const float* W0  = (const float*)d_in[5];  const float* B0 = (const float*)d_in[6];
    const float* W1  = (const float*)d_in[7];  const float* B1 = (const float*)d_in[8];
    const float* W2  = (const float*)d_in[9];  const float* B2 = (const float*)d_in[10];
    const float* W3  = (const float*)d_in[11]; const float* B3 = (const float*)d_in[12];
    const float* W4  = (const float*)d_in[13]; const float* B4 = (const float*)d_in[14];
    const float* OW0 = (const float*)d_in[15]; const float* OB0 = (const float*)d_in[16];
    const float* OW1 = (const float*)d_in[17]; const float* OB1 = (const float*)d_in[18];

    const int n_nodes = in_sizes[1] / 4;
    const int n_edges = in_sizes[3];

    // workspace layout (all 256-B aligned)
    auto align256 = [](size_t v) { return (v + 255) & ~(size_t)255; };
    char* ws = (char*)d_ws;
    const size_t copy_elems = (size_t)n_nodes * 50;
    size_t o = 0;
    u16*   Wt       = (u16*)(ws + o);  o = WS_HDR;
    float* Ep       = (float*)(ws + o); o = align256(o + copy_elems * sizeof(float));
    u32*   offs     = (u32*)(ws + o);  o = align256(o + (size_t)(n_nodes + 1) * 4);
    u32*   cursor   = (u32*)(ws + o);  o = align256(o + (size_t)n_nodes * 4);  // also hist cnt
    u32*   bsum     = (u32*)(ws + o);  o = align256(o + 512 * 4);
    int2*  sg_perm  = (int2*)(ws + o); o = align256(o + (size_t)n_edges * 8);

    const int NB  = (n_nodes + 255) / 256;          // 391 for 100K (scan2 handles <=512)
    const int EBK = (n_edges + 255) / 256;

    prep_all<<<dim3(32, 5), 256, 0, stream>>>(W0, W1, W2, W3, W4,
                                              B0, B1, B2, B3, B4, Wt);
    hipMemsetAsync(Ep, 0, copy_elems * sizeof(float), stream);
    hipMemsetAsync(cursor, 0, (size_t)n_nodes * 4, stream);

    // counting sort of edges by tgt
    hist_kernel <<<EBK, 256, 0, stream>>>(tgt, cursor, n_edges);
    scan1_kernel<<<NB, 256, 0, stream>>>(cursor, offs, bsum, n_nodes);
    scan2_kernel<<<1, 512, 0, stream>>>(bsum, NB);
    scan3_kernel<<<NB, 256, 0, stream>>>(offs, bsum, cursor, n_nodes, n_edges);
    perm_kernel <<<EBK, 256, 0, stream>>>(src, tgt, cursor, sg_perm, n_edges);

    edge_kernel<<<(n_edges + BLK_E - 1) / BLK_E, NTHR, 0, stream>>>(
        t, x, Ofx, sg_perm, Wt, Ep, n_edges);

    node_kernel<<<(n_nodes + 63) / 64, 256, 0, stream>>>(
        Ep, OW0, OB0, OW1, OB1, (float*)d_out, n_nodes);
}

// Round 6
// 903.584 us; speedup vs baseline: 1.0137x; 1.0040x over previous
//
#include <hip/hip_runtime.h>
#include <hip/hip_bf16.h>

typedef unsigned short u16;
typedef unsigned int u32;
typedef __attribute__((ext_vector_type(8))) short short8;
typedef __attribute__((ext_vector_type(4))) float f32x4;

constexpr int SA     = 192;    // act row stride (bf16): 384 B (96 dw, bank-neutral)
constexpr int BLK_E  = 128;    // edges per block
constexpr int NTHR   = 512;    // 8 waves = 4 M-groups x 2 N-groups (5/5 N-split)
constexpr int CHUNK  = 512;    // u16 elems per (ks,j) fragment chunk = 1 KB
constexpr int WSLOT  = 50 * CHUNK;              // 25600 elems per layer (5 ks x 10 j)
constexpr size_t WS_HDR   = 262144;             // weights header

// slice schedule: s=0 -> (L0,ks0); s=1..15 -> L1..L3 (5 ks each); s=16..20 -> L4
constexpr int Ls (int s) { return s == 0 ? 0 : (s <= 15 ? 1 + (s - 1) / 5 : 4); }
constexpr int Kss(int s) { return s == 0 ? 0 : (s <= 15 ? (s - 1) % 5 : s - 16); }

// act XOR-swizzle (R4): 16B-block idx ^= row&7; SA=192 keeps row base bank-neutral.
__device__ __forceinline__ int aswz(int row, int elem) {
    return row * SA + (elem ^ ((row & 7) << 3));
}

__device__ __forceinline__ u16 f2bf(float f) {  // RNE (prep only)
    union { float f; unsigned u; } c; c.f = f;
    return (u16)((c.u + 0x7fffu + ((c.u >> 16) & 1u)) >> 16);
}
__device__ __forceinline__ unsigned pk_bf16(float a, float b) {  // v_cvt_pk_bf16_f32
    float2 f; f.x = a; f.y = b;
    __hip_bfloat162 h = __float22bfloat162_rn(f);
    return *(unsigned*)&h;
}

// async global->LDS 16B per lane: LDS dest = uniform base + lane*16 (linear).
typedef __attribute__((address_space(3))) u16 as3_u16;
typedef const __attribute__((address_space(1))) u16 as1_u16;
__device__ __forceinline__ void async16(u16* lds_dst, const u16* gsrc) {
    __builtin_amdgcn_global_load_lds((as1_u16*)gsrc, (as3_u16*)lds_dst, 16, 0, 0);
}

// act k'-storage (5/5 N-split):
__device__ __forceinline__ int kperm(int kp) {
    if (kp < 64)  return (kp & 3) * 16 + (kp >> 2);
    if (kp < 128) { const int m = kp - 64; return (5 + (m & 3)) * 16 + (m >> 2); }
    if (kp < 144) return 4 * 16 + (kp - 128);
    if (kp < 160) return 9 * 16 + (kp - 144);
    return 1 << 30;
}

// ---- prep: weights -> fragment-ordered chunks, BIAS FOLDED IN --------------
__global__ void prep_all(const float* __restrict__ W0, const float* __restrict__ W1,
                         const float* __restrict__ W2, const float* __restrict__ W3,
                         const float* __restrict__ W4,
                         const float* __restrict__ B0, const float* __restrict__ B1,
                         const float* __restrict__ B2, const float* __restrict__ B3,
                         const float* __restrict__ B4,
                         u16* __restrict__ Wt)
{
    const int l = blockIdx.y;
    const float* W; const float* B; int DI, DO; bool perm;
    if      (l == 0) { W = W0; B = B0; DI = 13;  DO = 150; perm = false; }
    else if (l == 1) { W = W1; B = B1; DI = 150; DO = 150; perm = true;  }
    else if (l == 2) { W = W2; B = B2; DI = 150; DO = 150; perm = true;  }
    else if (l == 3) { W = W3; B = B3; DI = 150; DO = 150; perm = true;  }
    else             { W = W4; B = B4; DI = 150; DO = 50;  perm = true;  }
    const int kbias = (l == 0) ? 13 : 150;      // constant-1 input row
    u16* dst = Wt + (size_t)l * WSLOT;
    for (int idx = blockIdx.x * blockDim.x + threadIdx.x; idx < WSLOT;
         idx += gridDim.x * blockDim.x) {
        const int chunk = idx / CHUNK;            // = ks*10 + j
        const int within = idx - chunk * CHUNK;
        const int lane = within >> 3, e = within & 7;
        const int ks = chunk / 10, j = chunk - ks * 10;
        const int c = lane & 15, q = lane >> 4;
        const int n = j * 16 + c;
        const int kphys = ks * 32 + q * 8 + e;
        const int klog = perm ? kperm(kphys) : kphys;
        float v = 0.f;
        if (n < DO) {
            if (klog < DI)          v = W[klog * DO + n];
            else if (klog == kbias) v = B[n];     // folded bias row
        }
        dst[idx] = f2bf(v);
    }
}

// ---- epilogue: relu + packed bf16, k'-permuted swizzled store --------------
__device__ __forceinline__ void epilogue(u16* act, int mg, int ng, int col, int quad,
                                         f32x4 (&acc)[2][5])
{
#pragma unroll
    for (int mtl = 0; mtl < 2; ++mtl)
#pragma unroll
        for (int r = 0; r < 4; ++r) {
            const int row = (mg * 2 + mtl) * 16 + quad * 4 + r;
            uint2 pk;
            pk.x = pk_bf16(fmaxf(acc[mtl][0][r], 0.f), fmaxf(acc[mtl][1][r], 0.f));
            pk.y = pk_bf16(fmaxf(acc[mtl][2][r], 0.f), fmaxf(acc[mtl][3][r], 0.f));
            *(uint2*)&act[aswz(row, ng * 64 + col * 4)] = pk;      // tiles 0-3 / 5-8
            u16 sv = (u16)pk_bf16(fmaxf(acc[mtl][4][r], 0.f), 0.f);
            if (ng == 1 && col == 6) sv = 0x3F80;                  // n=150 := 1.0
            act[aswz(row, 128 + ng * 16 + col)] = sv;              // tile 4 / 9
        }
}

// ====================== counting sort of edges by tgt =======================
__global__ void hist_kernel(const int* __restrict__ tgt, u32* __restrict__ cnt,
                            int n_edges)
{
    const int e = blockIdx.x * blockDim.x + threadIdx.x;
    if (e < n_edges) atomicAdd(&cnt[tgt[e]], 1u);
}

__global__ void scan1_kernel(const u32* __restrict__ cnt, u32* __restrict__ offs,
                             u32* __restrict__ bsum, int n)
{
    __shared__ u32 s[256];
    const int i = blockIdx.x * 256 + threadIdx.x;
    const u32 v = (i < n) ? cnt[i] : 0u;
    s[threadIdx.x] = v; __syncthreads();
#pragma unroll
    for (int d = 1; d < 256; d <<= 1) {
        const u32 t = (threadIdx.x >= d) ? s[threadIdx.x - d] : 0u;
        __syncthreads();
        s[threadIdx.x] += t;
        __syncthreads();
    }
    if (i < n) offs[i] = s[threadIdx.x] - v;         // exclusive within block
    if (threadIdx.x == 255) bsum[blockIdx.x] = s[255];
}

__global__ void scan2_kernel(u32* __restrict__ bsum, int nb)   // nb <= 512
{
    __shared__ u32 s[512];
    const int i = threadIdx.x;
    const u32 v = (i < nb) ? bsum[i] : 0u;
    s[i] = v; __syncthreads();
#pragma unroll
    for (int d = 1; d < 512; d <<= 1) {
        const u32 t = (i >= d) ? s[i - d] : 0u;
        __syncthreads();
        s[i] += t;
        __syncthreads();
    }
    if (i < nb) bsum[i] = s[i] - v;                  // exclusive block bases
}

__global__ void scan3_kernel(u32* __restrict__ offs, const u32* __restrict__ bsum,
                             u32* __restrict__ cursor, int n, int n_edges)
{
    const int i = blockIdx.x * 256 + threadIdx.x;
    if (i < n) {
        const u32 o = offs[i] + bsum[blockIdx.x];
        offs[i] = o;
        cursor[i] = o;
    }
    if (blockIdx.x == 0 && threadIdx.x == 0) offs[n] = (u32)n_edges;
}

__global__ void perm_kernel(const int* __restrict__ src, const int* __restrict__ tgt,
                            u32* __restrict__ cursor, int2* __restrict__ sg,
                            int n_edges)
{
    const int e = blockIdx.x * blockDim.x + threadIdx.x;
    if (e < n_edges) {
        const int g = tgt[e];
        const u32 pos = atomicAdd(&cursor[g], 1u);
        sg[pos] = make_int2(src[e], g);
    }
}

// ------------------------------- Edge kernel --------------------------------
// Edges SORTED BY TGT. 128 edges / 8 waves (4mg x 2ng).
// B WEIGHTS STAGED ONCE PER BLOCK into LDS (global_load_lds, double-buffered):
// L2 weight traffic per edge drops 4x vs per-wave register loads.
__global__ __launch_bounds__(NTHR, 4) void edge_kernel(
    const float* __restrict__ t, const float* __restrict__ x, const float* __restrict__ Ofx,
    const int2* __restrict__ sgp,
    const u16* __restrict__ Wt,
    float* __restrict__ Ep, int n_edges)
{
    __shared__ __align__(16) u16 act[BLK_E * SA];      // 49152 B (f32 E-tile reuse)
    __shared__ __align__(16) u16 Bs[2][10 * CHUNK];    // 20480 B slice double-buffer
    __shared__ int tgt_s[BLK_E];                       // 512 B

    const int tid  = threadIdx.x;
    const int lane = tid & 63;
    const int wv   = tid >> 6;         // 0..7
    const int mg   = wv >> 1;          // M-group: edges [mg*32, mg*32+32)
    const int ng   = wv & 1;           // N-group: chunks [ng*5, ng*5+5)
    const int col  = lane & 15;
    const int quad = lane >> 4;
    const int jb   = ng * 5;

    // ---- stage slice 0 into Bs[0]: wave w loads chunk w (+8+w for w<2) -----
    {
        const u16* base = Wt;          // l=0, ks=0
        async16(&Bs[0][wv * CHUNK], base + wv * CHUNK + lane * 8);
        if (wv < 2)
            async16(&Bs[0][(8 + wv) * CHUNK], base + (8 + wv) * CHUNK + lane * 8);
    }

    // ---- gather R': each wave loads 16 edges (lanes 0-15) ------------------
    if (lane < 16) {
        const int e = wv * 16 + lane;
        const long long ge = (long long)blockIdx.x * BLK_E + e;
        const bool valid = ge < n_edges;
        const int2 sg = valid ? sgp[ge] : make_int2(0, 0);
        const int s = sg.x;
        const int g = valid ? sg.y : -1;
        const float4 xs = valid ? *(const float4*)&x[(size_t)s * 4] : float4{0, 0, 0, 0};
        const float2 os = valid ? *(const float2*)&Ofx[(size_t)s * 2] : float2{0, 0};
        const float4 xg = valid ? *(const float4*)&x[(size_t)sg.y * 4] : float4{0, 0, 0, 0};
        const float2 og = valid ? *(const float2*)&Ofx[(size_t)sg.y * 2] : float2{0, 0};
        const float tv = valid ? t[0] : 0.f;
        uint4 w0, w1;
        w0.x = pk_bf16(xs.x, xs.y); w0.y = pk_bf16(xs.z, xs.w);
        w0.z = pk_bf16(os.x, os.y); w0.w = pk_bf16(xg.x, xg.y);
        w1.x = pk_bf16(xg.z, xg.w); w1.y = pk_bf16(og.x, og.y);
        w1.z = pk_bf16(tv, 1.0f);   w1.w = 0u;     // k=13 := 1 (bias neuron)
        *(uint4*)&act[aswz(e, 0)]  = w0;
        *(uint4*)&act[aswz(e, 8)]  = w1;
        *(uint4*)&act[aswz(e, 16)] = uint4{0, 0, 0, 0};
        *(uint4*)&act[aswz(e, 24)] = uint4{0, 0, 0, 0};
        tgt_s[e] = g;
    }
    __syncthreads();        // drains stage-0 (vmcnt 0) + gather LDS writes

    const f32x4 z = {0.f, 0.f, 0.f, 0.f};
    f32x4 acc[2][5];
    short8 Af[2], Bc[5];

    // ---- s=0..15: L0..L3 (layer ends at s=0,5,10,15) -----------------------
#pragma unroll
    for (int s = 0; s <= 15; ++s) {
        const int ks = Kss(s);
        const bool first = (s == 0) || (ks == 0);
        const bool last  = (s == 0) || (ks == 4);
        // stage slice s+1 into the other buffer (issued early, lands at barrier)
        {
            const int sn = s + 1;
            const u16* base = Wt + (size_t)Ls(sn) * WSLOT
                                 + (size_t)(Kss(sn) * 10) * CHUNK;
            u16* bd = &Bs[sn & 1][0];
            async16(&bd[wv * CHUNK], base + wv * CHUNK + lane * 8);
            if (wv < 2)
                async16(&bd[(8 + wv) * CHUNK], base + (8 + wv) * CHUNK + lane * 8);
        }
        // B frags from LDS (stride-1 per lane, conflict-free)
#pragma unroll
        for (int jj = 0; jj < 5; ++jj)
            Bc[jj] = *(const short8*)&Bs[s & 1][(jb + jj) * CHUNK + lane * 8];
        // A frags (swizzled act)
#pragma unroll
        for (int mtl = 0; mtl < 2; ++mtl)
            Af[mtl] = *(const short8*)&act[aswz((mg * 2 + mtl) * 16 + col,
                                                ks * 32 + quad * 8)];
#pragma unroll
        for (int jj = 0; jj < 5; ++jj)
#pragma unroll
            for (int mtl = 0; mtl < 2; ++mtl) {
                if (first)
                    acc[mtl][jj] = __builtin_amdgcn_mfma_f32_16x16x32_bf16(
                        Af[mtl], Bc[jj], z, 0, 0, 0);
                else
                    acc[mtl][jj] = __builtin_amdgcn_mfma_f32_16x16x32_bf16(
                        Af[mtl], Bc[jj], acc[mtl][jj], 0, 0, 0);
            }
        __syncthreads();    // slice reads done + staged s+1 landed (vmcnt drain)
        if (last) {
            epilogue(act, mg, ng, col, quad, acc);
            __syncthreads();                // epilogue visible
        }
    }

    // ---- s=16..20: L4 — one M-tile per wave (mt4 = wv), N=4 chunks ---------
    const int mt4 = wv;
    f32x4 acc4[4];
#pragma unroll
    for (int s = 16; s <= 20; ++s) {
        const int ks = s - 16;
        if (s < 20) {
            const int sn = s + 1;
            const u16* base = Wt + (size_t)4 * WSLOT
                                 + (size_t)(Kss(sn) * 10) * CHUNK;
            u16* bd = &Bs[sn & 1][0];
            async16(&bd[wv * CHUNK], base + wv * CHUNK + lane * 8);
            if (wv < 2)
                async16(&bd[(8 + wv) * CHUNK], base + (8 + wv) * CHUNK + lane * 8);
        }
        short8 B4[4];
#pragma unroll
        for (int jj = 0; jj < 4; ++jj)
            B4[jj] = *(const short8*)&Bs[s & 1][jj * CHUNK + lane * 8];
        const short8 A4 = *(const short8*)&act[aswz(mt4 * 16 + col,
                                                    ks * 32 + quad * 8)];
#pragma unroll
        for (int jj = 0; jj < 4; ++jj) {
            if (ks == 0)
                acc4[jj] = __builtin_amdgcn_mfma_f32_16x16x32_bf16(
                    A4, B4[jj], z, 0, 0, 0);
            else
                acc4[jj] = __builtin_amdgcn_mfma_f32_16x16x32_bf16(
                    A4, B4[jj], acc4[jj], 0, 0, 0);
        }
        __syncthreads();    // slice reads done (also lands next stage)
    }

    // ---- segment-reduced scatter (edges sorted by tgt) ---------------------
    float* actF = (float*)act;              // reuse act LDS as f32 [128][52]
#pragma unroll
    for (int jj = 0; jj < 4; ++jj) {
        const int n = jj * 16 + col;
        if (n < 50) {
#pragma unroll
            for (int r = 0; r < 4; ++r)
                actF[(mt4 * 16 + quad * 4 + r) * 52 + n] = acc4[jj][r];
        }
    }
    __syncthreads();                        // E tile visible
    // 400 threads: (eighth h, col c). Scan 16 sorted rows, one atomic per run
    // segment (runs crossing sections -> extra atomic, OK).
    if (tid < 400) {
        const int h = tid / 50;
        const int c = tid - h * 50;
        const int r0 = h * 16;
        int   cur = tgt_s[r0];
        float a   = 0.f;
        for (int r = r0; r < r0 + 16; ++r) {
            const int   g = tgt_s[r];
            const float v = actF[r * 52 + c];
            if (g != cur) {
                if (cur >= 0) atomicAdd(&Ep[(size_t)cur * 50 + c], a);
                a = 0.f; cur = g;
            }
            a += v;
        }
        if (cur >= 0) atomicAdd(&Ep[(size_t)cur * 50 + c], a);
    }
}

// ---------------- Node kernel: fO MLP (fp32 VALU) ---------------------------
template<int DI, int DO, bool RELU>
__device__ __forceinline__ void mlp_layer_t(
    const float* __restrict__ W, const float* __restrict__ B,
    float (*in)[64], float (*out)[64], int tid)
{
    const int et = tid & 15;
    const int jt = tid >> 4;
    constexpr int NG = (DO + 15) / 16;

    float acc0[NG], acc1[NG], acc2[NG], acc3[NG];
#pragma unroll
    for (int g = 0; g < NG; ++g) {
        const int j = jt + 16 * g;
        const float bb = (j < DO) ? B[j] : 0.f;
        acc0[g] = bb; acc1[g] = bb; acc2[g] = bb; acc3[g] = bb;
    }
    for (int k = 0; k < DI; ++k) {
        const float4 a = *(const float4*)&in[k][et * 4];
#pragma unroll
        for (int g = 0; g < NG; ++g) {
            const int j = jt + 16 * g;
            const float wv = (j < DO) ? W[k * DO + j] : 0.f;
            acc0[g] = fmaf(a.x, wv, acc0[g]);
            acc1[g] = fmaf(a.y, wv, acc1[g]);
            acc2[g] = fmaf(a.z, wv, acc2[g]);
            acc3[g] = fmaf(a.w, wv, acc3[g]);
        }
    }
#pragma unroll
    for (int g = 0; g < NG; ++g) {
        const int j = jt + 16 * g;
        if (j < DO) {
            float4 v; v.x = acc0[g]; v.y = acc1[g]; v.z = acc2[g]; v.w = acc3[g];
            if (RELU) {
                v.x = fmaxf(v.x, 0.f); v.y = fmaxf(v.y, 0.f);
                v.z = fmaxf(v.z, 0.f); v.w = fmaxf(v.w, 0.f);
            }
            *(float4*)&out[j][et * 4] = v;
        }
    }
}

__global__ __launch_bounds__(256, 2) void node_kernel(
    const float* __restrict__ Ep,
    const float* __restrict__ W0, const float* __restrict__ B0,
    const float* __restrict__ W1, const float* __restrict__ B1,
    float* __restrict__ P, int n_nodes)
{
    __shared__ float bufA[104][64];
    __shared__ float bufB[104][64];
    const int tid = threadIdx.x;
    const int n0  = blockIdx.x * 64;

    for (int idx = tid; idx < 64 * 50; idx += 256) {
        const int e = idx / 50;
        const int k = idx - e * 50;
        const int n = n0 + e;
        bufA[k][e] = (n < n_nodes) ? Ep[(size_t)n * 50 + k] : 0.f;
    }
    __syncthreads();
    mlp_layer_t<50, 100, true >(W0, B0, bufA, bufB, tid); __syncthreads();
    mlp_layer_t<100, 4, false>(W1, B1, bufB, bufA, tid); __syncthreads();
    for (int idx = tid; idx < 64 * 4; idx += 256) {
        const int e = idx & 63;
        const int j = idx >> 6;
        const int n = n0 + e;
        if (n < n_nodes) P[(size_t)n * 4 + j] = bufA[j][e];
    }
}

// ------------------------------- launcher -----------------------------------
extern "C" void kernel_launch(void* const* d_in, const int* in_sizes, int n_in,
                              void* d_out, int out_size, void* d_ws, size_t ws_size,
                              hipStream_t stream)
{
    const float* t   = (const float*)d_in[0];
    const float* x   = (const float*)d_in[1];
    const float* Ofx = (const float*)d_in[2];
    const int*   src = (const int*)d_in[3];
    const int*   tgt = (const int*)d_in[4];
    const float* W0  = (const float*)d_in[5];  const float* B0 = (const float*)d_in[6];
    const float* W1  = (const float*)d_in[7];  const float* B1 = (const float*)d_in[8];
    const float* W2  = (const float*)d_in[9];  const float* B2 = (const float*)d_in[10];
    const float* W3  = (const float*)d_in[11]; const float* B3 = (const float*)d_in[12];
    const float* W4  = (const float*)d_in[13]; const float* B4 = (const float*)d_in[14];
    const float* OW0 = (const float*)d_in[15]; const float* OB0 = (const float*)d_in[16];
    const float* OW1 = (const float*)d_in[17]; const float* OB1 = (const float*)d_in[18];

    const int n_nodes = in_sizes[1] / 4;
    const int n_edges = in_sizes[3];

    // workspace layout (all 256-B aligned)
    auto align256 = [](size_t v) { return (v + 255) & ~(size_t)255; };
    char* ws = (char*)d_ws;
    const size_t copy_elems = (size_t)n_nodes * 50;
    size_t o = 0;
    u16*   Wt       = (u16*)(ws + o);  o = WS_HDR;
    float* Ep       = (float*)(ws + o); o = align256(o + copy_elems * sizeof(float));
    u32*   offs     = (u32*)(ws + o);  o = align256(o + (size_t)(n_nodes + 1) * 4);
    u32*   cursor   = (u32*)(ws + o);  o = align256(o + (size_t)n_nodes * 4);  // also hist cnt
    u32*   bsum     = (u32*)(ws + o);  o = align256(o + 512 * 4);
    int2*  sg_perm  = (int2*)(ws + o); o = align256(o + (size_t)n_edges * 8);

    const int NB  = (n_nodes + 255) / 256;          // 391 for 100K (scan2 handles <=512)
    const int EBK = (n_edges + 255) / 256;

    prep_all<<<dim3(32, 5), 256, 0, stream>>>(W0, W1, W2, W3, W4,
                                              B0, B1, B2, B3, B4, Wt);
    hipMemsetAsync(Ep, 0, copy_elems * sizeof(float), stream);
    hipMemsetAsync(cursor, 0, (size_t)n_nodes * 4, stream);

    // counting sort of edges by tgt
    hist_kernel <<<EBK, 256, 0, stream>>>(tgt, cursor, n_edges);
    scan1_kernel<<<NB, 256, 0, stream>>>(cursor, offs, bsum, n_nodes);
    scan2_kernel<<<1, 512, 0, stream>>>(bsum, NB);
    scan3_kernel<<<NB, 256, 0, stream>>>(offs, bsum, cursor, n_nodes, n_edges);
    perm_kernel <<<EBK, 256, 0, stream>>>(src, tgt, cursor, sg_perm, n_edges);

    edge_kernel<<<(n_edges + BLK_E - 1) / BLK_E, NTHR, 0, stream>>>(
        t, x, Ofx, sg_perm, Wt, Ep, n_edges);

    node_kernel<<<(n_nodes + 63) / 64, 256, 0, stream>>>(
        Ep, OW0, OB0, OW1, OB1, (float*)d_out, n_nodes);
}

// Round 7
// 884.930 us; speedup vs baseline: 1.0351x; 1.0211x over previous
//
#include <hip/hip_runtime.h>
#include <hip/hip_bf16.h>

typedef unsigned short u16;
typedef unsigned int u32;
typedef __attribute__((ext_vector_type(8))) short short8;
typedef __attribute__((ext_vector_type(4))) float f32x4;

constexpr int SA     = 192;    // act row stride (bf16): 384 B (96 dw, bank-neutral)
constexpr int BLK_E  = 128;    // 4 waves x 32 edges, all waves independent
constexpr int NTHR   = 256;
constexpr int CHUNK  = 512;    // u16 elems per (ks,j) fragment chunk = 1 KB
constexpr int WSLOT  = 50 * CHUNK;              // elems per layer (5 ks x 10 j)
constexpr size_t WS_HDR   = 262144;             // weights header

// slice schedule: s=0 -> (L0,ks0); s=1..15 -> L1..L3 (5 ks each); s=16..20 -> L4
constexpr int Ls (int s) { return s == 0 ? 0 : (s <= 15 ? 1 + (s - 1) / 5 : 4); }
constexpr int Kss(int s) { return s == 0 ? 0 : (s <= 15 ? (s - 1) % 5 : s - 16); }

// act XOR-swizzle: 16B-block idx ^= row&7; SA=192 keeps row base bank-neutral.
__device__ __forceinline__ int aswz(int row, int elem) {
    return row * SA + (elem ^ ((row & 7) << 3));
}

__device__ __forceinline__ u16 f2bf(float f) {  // RNE (prep only)
    union { float f; unsigned u; } c; c.f = f;
    return (u16)((c.u + 0x7fffu + ((c.u >> 16) & 1u)) >> 16);
}
__device__ __forceinline__ unsigned pk_bf16(float a, float b) {  // v_cvt_pk_bf16_f32
    float2 f; f.x = a; f.y = b;
    __hip_bfloat162 h = __float22bfloat162_rn(f);
    return *(unsigned*)&h;
}

// act k'-storage permutation (tiles 0-3 / 4 / 5-8 / 9)
__device__ __forceinline__ int kperm(int kp) {
    if (kp < 64)  return (kp & 3) * 16 + (kp >> 2);
    if (kp < 128) { const int m = kp - 64; return (5 + (m & 3)) * 16 + (m >> 2); }
    if (kp < 144) return 4 * 16 + (kp - 128);
    if (kp < 160) return 9 * 16 + (kp - 144);
    return 1 << 30;
}

// ---- prep: weights -> fragment-ordered chunks, BIAS FOLDED IN --------------
__global__ void prep_all(const float* __restrict__ W0, const float* __restrict__ W1,
                         const float* __restrict__ W2, const float* __restrict__ W3,
                         const float* __restrict__ W4,
                         const float* __restrict__ B0, const float* __restrict__ B1,
                         const float* __restrict__ B2, const float* __restrict__ B3,
                         const float* __restrict__ B4,
                         u16* __restrict__ Wt)
{
    const int l = blockIdx.y;
    const float* W; const float* B; int DI, DO; bool perm;
    if      (l == 0) { W = W0; B = B0; DI = 13;  DO = 150; perm = false; }
    else if (l == 1) { W = W1; B = B1; DI = 150; DO = 150; perm = true;  }
    else if (l == 2) { W = W2; B = B2; DI = 150; DO = 150; perm = true;  }
    else if (l == 3) { W = W3; B = B3; DI = 150; DO = 150; perm = true;  }
    else             { W = W4; B = B4; DI = 150; DO = 50;  perm = true;  }
    const int kbias = (l == 0) ? 13 : 150;      // constant-1 input row
    u16* dst = Wt + (size_t)l * WSLOT;
    for (int idx = blockIdx.x * blockDim.x + threadIdx.x; idx < WSLOT;
         idx += gridDim.x * blockDim.x) {
        const int chunk = idx / CHUNK;            // = ks*10 + j
        const int within = idx - chunk * CHUNK;
        const int lane = within >> 3, e = within & 7;
        const int ks = chunk / 10, j = chunk - ks * 10;
        const int c = lane & 15, q = lane >> 4;
        const int n = j * 16 + c;
        const int kphys = ks * 32 + q * 8 + e;
        const int klog = perm ? kperm(kphys) : kphys;
        float v = 0.f;
        if (n < DO) {
            if (klog < DI)          v = W[klog * DO + n];
            else if (klog == kbias) v = B[n];     // folded bias row
        }
        dst[idx] = f2bf(v);
    }
}

// ---- B half-slice load: 5 (or 4) coalesced 1 KB chunks -> registers --------
__device__ __forceinline__ void loadHalf(const u16* __restrict__ Wt,
                                         int l, int ks, int g, int nch,
                                         int lane, short8* buf)
{
    const u16* base = Wt + (size_t)l * WSLOT + (size_t)(ks * 10 + g * 5) * CHUNK
                         + lane * 8;
#pragma unroll
    for (int jj = 0; jj < 5; ++jj)
        if (jj < nch) buf[jj] = *(const short8*)&base[jj * CHUNK];
}

// ---- full-width epilogue: relu + packed bf16, k'-permuted swizzled store ---
__device__ __forceinline__ void epilogueF(u16* act, int ebase, int col, int quad,
                                          f32x4 (&acc)[2][10])
{
#pragma unroll
    for (int mtl = 0; mtl < 2; ++mtl)
#pragma unroll
        for (int r = 0; r < 4; ++r) {
            const int row = ebase + mtl * 16 + quad * 4 + r;
            uint2 p0, p1;
            p0.x = pk_bf16(fmaxf(acc[mtl][0][r], 0.f), fmaxf(acc[mtl][1][r], 0.f));
            p0.y = pk_bf16(fmaxf(acc[mtl][2][r], 0.f), fmaxf(acc[mtl][3][r], 0.f));
            p1.x = pk_bf16(fmaxf(acc[mtl][5][r], 0.f), fmaxf(acc[mtl][6][r], 0.f));
            p1.y = pk_bf16(fmaxf(acc[mtl][7][r], 0.f), fmaxf(acc[mtl][8][r], 0.f));
            *(uint2*)&act[aswz(row, col * 4)]      = p0;   // tiles 0-3
            *(uint2*)&act[aswz(row, 64 + col * 4)] = p1;   // tiles 5-8
            act[aswz(row, 128 + col)] =
                (u16)pk_bf16(fmaxf(acc[mtl][4][r], 0.f), 0.f);   // tile 4
            u16 sv = (u16)pk_bf16(fmaxf(acc[mtl][9][r], 0.f), 0.f);
            if (col == 6) sv = 0x3F80;                     // n=150 := 1.0 (bias)
            act[aswz(row, 144 + col)] = sv;                // tile 9
        }
}

// ====================== counting sort of edges by tgt =======================
__global__ void hist_kernel(const int* __restrict__ tgt, u32* __restrict__ cnt,
                            int n_edges)
{
    const int e = blockIdx.x * blockDim.x + threadIdx.x;
    if (e < n_edges) atomicAdd(&cnt[tgt[e]], 1u);
}

__global__ void scan1_kernel(const u32* __restrict__ cnt, u32* __restrict__ offs,
                             u32* __restrict__ bsum, int n)
{
    __shared__ u32 s[256];
    const int i = blockIdx.x * 256 + threadIdx.x;
    const u32 v = (i < n) ? cnt[i] : 0u;
    s[threadIdx.x] = v; __syncthreads();
#pragma unroll
    for (int d = 1; d < 256; d <<= 1) {
        const u32 t = (threadIdx.x >= d) ? s[threadIdx.x - d] : 0u;
        __syncthreads();
        s[threadIdx.x] += t;
        __syncthreads();
    }
    if (i < n) offs[i] = s[threadIdx.x] - v;         // exclusive within block
    if (threadIdx.x == 255) bsum[blockIdx.x] = s[255];
}

__global__ void scan2_kernel(u32* __restrict__ bsum, int nb)   // nb <= 512
{
    __shared__ u32 s[512];
    const int i = threadIdx.x;
    const u32 v = (i < nb) ? bsum[i] : 0u;
    s[i] = v; __syncthreads();
#pragma unroll
    for (int d = 1; d < 512; d <<= 1) {
        const u32 t = (i >= d) ? s[i - d] : 0u;
        __syncthreads();
        s[i] += t;
        __syncthreads();
    }
    if (i < nb) bsum[i] = s[i] - v;                  // exclusive block bases
}

__global__ void scan3_kernel(u32* __restrict__ offs, const u32* __restrict__ bsum,
                             u32* __restrict__ cursor, int n, int n_edges)
{
    const int i = blockIdx.x * 256 + threadIdx.x;
    if (i < n) {
        const u32 o = offs[i] + bsum[blockIdx.x];
        offs[i] = o;
        cursor[i] = o;
    }
    if (blockIdx.x == 0 && threadIdx.x == 0) offs[n] = (u32)n_edges;
}

__global__ void perm_kernel(const int* __restrict__ src, const int* __restrict__ tgt,
                            u32* __restrict__ cursor, int2* __restrict__ sg,
                            int n_edges)
{
    const int e = blockIdx.x * blockDim.x + threadIdx.x;
    if (e < n_edges) {
        const int g = tgt[e];
        const u32 pos = atomicAdd(&cursor[g], 1u);
        sg[pos] = make_int2(src[e], g);
    }
}

// ------------------------------- Edge kernel --------------------------------
// BARRIER-FREE: each wave owns 32 edges end-to-end. act rows, E-tile, and the
// run-scan are all wave-private (same-wave DS ordering needs no syncthreads).
// B: per-wave register loads, full N-width, 2-half-slice pipelined.
__global__ __launch_bounds__(NTHR, 3) void edge_kernel(
    const float* __restrict__ t, const float* __restrict__ x, const float* __restrict__ Ofx,
    const int2* __restrict__ sgp,
    const u16* __restrict__ Wt,
    float* __restrict__ Ep, int n_edges)
{
    __shared__ __align__(16) u16 act[BLK_E * SA];      // 49152 B, 32 rows per wave
    __shared__ int tgt_s[BLK_E];

    const int tid   = threadIdx.x;
    const int lane  = tid & 63;
    const int wv    = tid >> 6;        // 0..3
    const int ebase = wv * 32;         // this wave's 32 act rows
    const int col   = lane & 15;
    const int quad  = lane >> 4;

    // ---- gather R': this wave's 32 edges (lanes 0-31, one edge each) -------
    if (lane < 32) {
        const int e = ebase + lane;
        const long long ge = (long long)blockIdx.x * BLK_E + e;
        const bool valid = ge < n_edges;
        const int2 sg = valid ? sgp[ge] : make_int2(0, 0);
        const int g = valid ? sg.y : -1;
        const float4 xs = valid ? *(const float4*)&x[(size_t)sg.x * 4] : float4{0, 0, 0, 0};
        const float2 os = valid ? *(const float2*)&Ofx[(size_t)sg.x * 2] : float2{0, 0};
        const float4 xg = valid ? *(const float4*)&x[(size_t)sg.y * 4] : float4{0, 0, 0, 0};
        const float2 og = valid ? *(const float2*)&Ofx[(size_t)sg.y * 2] : float2{0, 0};
        const float tv = valid ? t[0] : 0.f;
        uint4 w0, w1;
        w0.x = pk_bf16(xs.x, xs.y); w0.y = pk_bf16(xs.z, xs.w);
        w0.z = pk_bf16(os.x, os.y); w0.w = pk_bf16(xg.x, xg.y);
        w1.x = pk_bf16(xg.z, xg.w); w1.y = pk_bf16(og.x, og.y);
        w1.z = pk_bf16(tv, 1.0f);   w1.w = 0u;     // k=13 := 1 (bias neuron)
        *(uint4*)&act[aswz(e, 0)]  = w0;
        *(uint4*)&act[aswz(e, 8)]  = w1;
        *(uint4*)&act[aswz(e, 16)] = uint4{0, 0, 0, 0};
        *(uint4*)&act[aswz(e, 24)] = uint4{0, 0, 0, 0};
        tgt_s[e] = g;
    }
    // no __syncthreads: same-wave DS ops are ordered; other waves never touch
    // this wave's rows.

    const f32x4 z = {0.f, 0.f, 0.f, 0.f};
    f32x4 acc[2][10];
    short8 Wb[2][5];
    short8 Af[2];

    // prologue: prefetch the two halves of slice 0
    loadHalf(Wt, 0, 0, 0, 5, lane, Wb[0]);
    loadHalf(Wt, 0, 0, 1, 5, lane, Wb[1]);

    // ---- s=0..15: L0..L3, full N width per wave ----------------------------
#pragma unroll
    for (int s = 0; s <= 15; ++s) {
        const int ks = Kss(s);
        const bool first = (s == 0) || (ks == 0);
        // A frags for this k-slice (wave-private rows)
#pragma unroll
        for (int mtl = 0; mtl < 2; ++mtl)
            Af[mtl] = *(const short8*)&act[aswz(ebase + mtl * 16 + col,
                                                ks * 32 + quad * 8)];
        // half G0: tiles 0-4
#pragma unroll
        for (int jj = 0; jj < 5; ++jj)
#pragma unroll
            for (int mtl = 0; mtl < 2; ++mtl)
                acc[mtl][jj] = __builtin_amdgcn_mfma_f32_16x16x32_bf16(
                    Af[mtl], Wb[0][jj], first ? z : acc[mtl][jj], 0, 0, 0);
        // refill buf0 with half h=2s+2
        if (s < 15) loadHalf(Wt, Ls(s + 1), Kss(s + 1), 0, 5, lane, Wb[0]);
        else        loadHalf(Wt, 4, 0, 0, 4, lane, Wb[0]);     // L4 ks=0
        // half G1: tiles 5-9
#pragma unroll
        for (int jj = 0; jj < 5; ++jj)
#pragma unroll
            for (int mtl = 0; mtl < 2; ++mtl)
                acc[mtl][5 + jj] = __builtin_amdgcn_mfma_f32_16x16x32_bf16(
                    Af[mtl], Wb[1][jj], first ? z : acc[mtl][5 + jj], 0, 0, 0);
        // refill buf1 with half h=2s+3
        if (s < 15) loadHalf(Wt, Ls(s + 1), Kss(s + 1), 1, 5, lane, Wb[1]);
        else        loadHalf(Wt, 4, 1, 0, 4, lane, Wb[1]);     // L4 ks=1
        // layer boundary: epilogue (wave-private rows; same-wave DS order)
        if (s == 0 || ks == 4)
            epilogueF(act, ebase, col, quad, acc);
    }

    // ---- L4: ks=0..4, N=50 (4 tiles), both M-tiles ------------------------
    f32x4 acc4[2][4];
#pragma unroll
    for (int ks = 0; ks < 5; ++ks) {
#pragma unroll
        for (int mtl = 0; mtl < 2; ++mtl)
            Af[mtl] = *(const short8*)&act[aswz(ebase + mtl * 16 + col,
                                                ks * 32 + quad * 8)];
#pragma unroll
        for (int jj = 0; jj < 4; ++jj)
#pragma unroll
            for (int mtl = 0; mtl < 2; ++mtl)
                acc4[mtl][jj] = __builtin_amdgcn_mfma_f32_16x16x32_bf16(
                    Af[mtl], Wb[ks & 1][jj], (ks == 0) ? z : acc4[mtl][jj], 0, 0, 0);
        if (ks + 2 <= 4) loadHalf(Wt, 4, ks + 2, 0, 4, lane, Wb[ks & 1]);
    }

    // ---- wave-private E tile + run-scan scatter ----------------------------
    // f32 [32][52] overlaid on this wave's OWN act rows (6656 B < 12288 B).
    float* actF = (float*)&act[ebase * SA];
#pragma unroll
    for (int mtl = 0; mtl < 2; ++mtl)
#pragma unroll
        for (int jj = 0; jj < 4; ++jj) {
            const int n = jj * 16 + col;
            if (n < 50) {
#pragma unroll
                for (int r = 0; r < 4; ++r)
                    actF[(mtl * 16 + quad * 4 + r) * 52 + n] = acc4[mtl][jj][r];
            }
        }
    // lanes 0-49: scan this wave's 32 sorted rows, one atomic per run segment
    if (lane < 50) {
        const int c = lane;
        int   cur = tgt_s[ebase];
        float a   = 0.f;
        for (int r = 0; r < 32; ++r) {
            const int   g = tgt_s[ebase + r];
            const float v = actF[r * 52 + c];
            if (g != cur) {
                if (cur >= 0) atomicAdd(&Ep[(size_t)cur * 50 + c], a);
                a = 0.f; cur = g;
            }
            a += v;
        }
        if (cur >= 0) atomicAdd(&Ep[(size_t)cur * 50 + c], a);
    }
}

// ---------------- Node kernel: fO MLP (fp32 VALU) ---------------------------
template<int DI, int DO, bool RELU>
__device__ __forceinline__ void mlp_layer_t(
    const float* __restrict__ W, const float* __restrict__ B,
    float (*in)[64], float (*out)[64], int tid)
{
    const int et = tid & 15;
    const int jt = tid >> 4;
    constexpr int NG = (DO + 15) / 16;

    float acc0[NG], acc1[NG], acc2[NG], acc3[NG];
#pragma unroll
    for (int g = 0; g < NG; ++g) {
        const int j = jt + 16 * g;
        const float bb = (j < DO) ? B[j] : 0.f;
        acc0[g] = bb; acc1[g] = bb; acc2[g] = bb; acc3[g] = bb;
    }
    for (int k = 0; k < DI; ++k) {
        const float4 a = *(const float4*)&in[k][et * 4];
#pragma unroll
        for (int g = 0; g < NG; ++g) {
            const int j = jt + 16 * g;
            const float wv = (j < DO) ? W[k * DO + j] : 0.f;
            acc0[g] = fmaf(a.x, wv, acc0[g]);
            acc1[g] = fmaf(a.y, wv, acc1[g]);
            acc2[g] = fmaf(a.z, wv, acc2[g]);
            acc3[g] = fmaf(a.w, wv, acc3[g]);
        }
    }
#pragma unroll
    for (int g = 0; g < NG; ++g) {
        const int j = jt + 16 * g;
        if (j < DO) {
            float4 v; v.x = acc0[g]; v.y = acc1[g]; v.z = acc2[g]; v.w = acc3[g];
            if (RELU) {
                v.x = fmaxf(v.x, 0.f); v.y = fmaxf(v.y, 0.f);
                v.z = fmaxf(v.z, 0.f); v.w = fmaxf(v.w, 0.f);
            }
            *(float4*)&out[j][et * 4] = v;
        }
    }
}

__global__ __launch_bounds__(256, 2) void node_kernel(
    const float* __restrict__ Ep,
    const float* __restrict__ W0, const float* __restrict__ B0,
    const float* __restrict__ W1, const float* __restrict__ B1,
    float* __restrict__ P, int n_nodes)
{
    __shared__ float bufA[104][64];
    __shared__ float bufB[104][64];
    const int tid = threadIdx.x;
    const int n0  = blockIdx.x * 64;

    for (int idx = tid; idx < 64 * 50; idx += 256) {
        const int e = idx / 50;
        const int k = idx - e * 50;
        const int n = n0 + e;
        bufA[k][e] = (n < n_nodes) ? Ep[(size_t)n * 50 + k] : 0.f;
    }
    __syncthreads();
    mlp_layer_t<50, 100, true >(W0, B0, bufA, bufB, tid); __syncthreads();
    mlp_layer_t<100, 4, false>(W1, B1, bufB, bufA, tid); __syncthreads();
    for (int idx = tid; idx < 64 * 4; idx += 256) {
        const int e = idx & 63;
        const int j = idx >> 6;
        const int n = n0 + e;
        if (n < n_nodes) P[(size_t)n * 4 + j] = bufA[j][e];
    }
}

// ------------------------------- launcher -----------------------------------
extern "C" void kernel_launch(void* const* d_in, const int* in_sizes, int n_in,
                              void* d_out, int out_size, void* d_ws, size_t ws_size,
                              hipStream_t stream)
{
    const float* t   = (const float*)d_in[0];
    const float* x   = (const float*)d_in[1];
    const float* Ofx = (const float*)d_in[2];
    const int*   src = (const int*)d_in[3];
    const int*   tgt = (const int*)d_in[4];
    const float* W0  = (const float*)d_in[5];  const float* B0 = (const float*)d_in[6];
    const float* W1  = (const float*)d_in[7];  const float* B1 = (const float*)d_in[8];
    const float* W2  = (const float*)d_in[9];  const float* B2 = (const float*)d_in[10];
    const float* W3  = (const float*)d_in[11]; const float* B3 = (const float*)d_in[12];
    const float* W4  = (const float*)d_in[13]; const float* B4 = (const float*)d_in[14];
    const float* OW0 = (const float*)d_in[15]; const float* OB0 = (const float*)d_in[16];
    const float* OW1 = (const float*)d_in[17]; const float* OB1 = (const float*)d_in[18];

    const int n_nodes = in_sizes[1] / 4;
    const int n_edges = in_sizes[3];

    // workspace layout (all 256-B aligned)
    auto align256 = [](size_t v) { return (v + 255) & ~(size_t)255; };
    char* ws = (char*)d_ws;
    const size_t copy_elems = (size_t)n_nodes * 50;
    size_t o = 0;
    u16*   Wt       = (u16*)(ws + o);  o = WS_HDR;
    float* Ep       = (float*)(ws + o); o = align256(o + copy_elems * sizeof(float));
    u32*   offs     = (u32*)(ws + o);  o = align256(o + (size_t)(n_nodes + 1) * 4);
    u32*   cursor   = (u32*)(ws + o);  o = align256(o + (size_t)n_nodes * 4);  // also hist cnt
    u32*   bsum     = (u32*)(ws + o);  o = align256(o + 512 * 4);
    int2*  sg_perm  = (int2*)(ws + o); o = align256(o + (size_t)n_edges * 8);

    const int NB  = (n_nodes + 255) / 256;          // 391 for 100K (scan2 handles <=512)
    const int EBK = (n_edges + 255) / 256;

    prep_all<<<dim3(32, 5), 256, 0, stream>>>(W0, W1, W2, W3, W4,
                                              B0, B1, B2, B3, B4, Wt);
    hipMemsetAsync(Ep, 0, copy_elems * sizeof(float), stream);
    hipMemsetAsync(cursor, 0, (size_t)n_nodes * 4, stream);

    // counting sort of edges by tgt
    hist_kernel <<<EBK, 256, 0, stream>>>(tgt, cursor, n_edges);
    scan1_kernel<<<NB, 256, 0, stream>>>(cursor, offs, bsum, n_nodes);
    scan2_kernel<<<1, 512, 0, stream>>>(bsum, NB);
    scan3_kernel<<<NB, 256, 0, stream>>>(offs, bsum, cursor, n_nodes, n_edges);
    perm_kernel <<<EBK, 256, 0, stream>>>(src, tgt, cursor, sg_perm, n_edges);

    edge_kernel<<<(n_edges + BLK_E - 1) / BLK_E, NTHR, 0, stream>>>(
        t, x, Ofx, sg_perm, Wt, Ep, n_edges);

    node_kernel<<<(n_nodes + 63) / 64, 256, 0, stream>>>(
        Ep, OW0, OB0, OW1, OB1, (float*)d_out, n_nodes);
}

// Round 8
// 870.637 us; speedup vs baseline: 1.0521x; 1.0164x over previous
//
#include <hip/hip_runtime.h>
#include <hip/hip_bf16.h>

typedef unsigned short u16;
typedef unsigned int u32;
typedef __attribute__((ext_vector_type(8))) short short8;
typedef __attribute__((ext_vector_type(4))) float f32x4;

constexpr int SA     = 192;    // act row stride (bf16): 384 B (96 dw, bank-neutral)
constexpr int BLK_E  = 128;    // 4 waves x 32 edges, all waves independent
constexpr int NTHR   = 256;
constexpr int CHUNK  = 512;    // u16 elems per (ks,j) fragment chunk = 1 KB
constexpr int WSLOT  = 50 * CHUNK;              // elems per layer (5 ks x 10 j)
constexpr size_t WS_HDR   = 262144;             // weights header

// slice schedule: s=0 -> (L0,ks0); s=1..15 -> L1..L3 (5 ks each); s=16..20 -> L4
constexpr int Ls (int s) { return s == 0 ? 0 : (s <= 15 ? 1 + (s - 1) / 5 : 4); }
constexpr int Kss(int s) { return s == 0 ? 0 : (s <= 15 ? (s - 1) % 5 : s - 16); }

// act XOR-swizzle: 16B-block idx ^= row&7; SA=192 keeps row base bank-neutral.
__device__ __forceinline__ int aswz(int row, int elem) {
    return row * SA + (elem ^ ((row & 7) << 3));
}

__device__ __forceinline__ u16 f2bf(float f) {  // RNE (prep only)
    union { float f; unsigned u; } c; c.f = f;
    return (u16)((c.u + 0x7fffu + ((c.u >> 16) & 1u)) >> 16);
}
__device__ __forceinline__ unsigned pk_bf16(float a, float b) {  // v_cvt_pk_bf16_f32
    float2 f; f.x = a; f.y = b;
    __hip_bfloat162 h = __float22bfloat162_rn(f);
    return *(unsigned*)&h;
}

// act k'-storage permutation (tiles 0-3 / 4 / 5-8 / 9)
__device__ __forceinline__ int kperm(int kp) {
    if (kp < 64)  return (kp & 3) * 16 + (kp >> 2);
    if (kp < 128) { const int m = kp - 64; return (5 + (m & 3)) * 16 + (m >> 2); }
    if (kp < 144) return 4 * 16 + (kp - 128);
    if (kp < 160) return 9 * 16 + (kp - 144);
    return 1 << 30;
}

// ---- prep: weights -> fragment-ordered chunks, BIAS FOLDED IN --------------
// blockIdx.y == 5: zero the sort cursor array (fused memset, saves a launch).
__global__ void prep_all(const float* __restrict__ W0, const float* __restrict__ W1,
                         const float* __restrict__ W2, const float* __restrict__ W3,
                         const float* __restrict__ W4,
                         const float* __restrict__ B0, const float* __restrict__ B1,
                         const float* __restrict__ B2, const float* __restrict__ B3,
                         const float* __restrict__ B4,
                         u16* __restrict__ Wt, u32* __restrict__ cursor, int n_nodes)
{
    const int l = blockIdx.y;
    if (l == 5) {
        for (int idx = blockIdx.x * blockDim.x + threadIdx.x; idx < n_nodes;
             idx += gridDim.x * blockDim.x)
            cursor[idx] = 0u;
        return;
    }
    const float* W; const float* B; int DI, DO; bool perm;
    if      (l == 0) { W = W0; B = B0; DI = 13;  DO = 150; perm = false; }
    else if (l == 1) { W = W1; B = B1; DI = 150; DO = 150; perm = true;  }
    else if (l == 2) { W = W2; B = B2; DI = 150; DO = 150; perm = true;  }
    else if (l == 3) { W = W3; B = B3; DI = 150; DO = 150; perm = true;  }
    else             { W = W4; B = B4; DI = 150; DO = 50;  perm = true;  }
    const int kbias = (l == 0) ? 13 : 150;      // constant-1 input row
    u16* dst = Wt + (size_t)l * WSLOT;
    for (int idx = blockIdx.x * blockDim.x + threadIdx.x; idx < WSLOT;
         idx += gridDim.x * blockDim.x) {
        const int chunk = idx / CHUNK;            // = ks*10 + j
        const int within = idx - chunk * CHUNK;
        const int lane = within >> 3, e = within & 7;
        const int ks = chunk / 10, j = chunk - ks * 10;
        const int c = lane & 15, q = lane >> 4;
        const int n = j * 16 + c;
        const int kphys = ks * 32 + q * 8 + e;
        const int klog = perm ? kperm(kphys) : kphys;
        float v = 0.f;
        if (n < DO) {
            if (klog < DI)          v = W[klog * DO + n];
            else if (klog == kbias) v = B[n];     // folded bias row
        }
        dst[idx] = f2bf(v);
    }
}

// ---- B half-slice load by half-index h (0..36) -> registers ----------------
// h<32: slice s=h/2 of L0..L3, group g=h&1, 5 chunks. h>=32: L4 ks=h-32, 4 chunks.
__device__ __forceinline__ void loadHalfH(const u16* __restrict__ Wt, int h,
                                          int lane, short8* buf)
{
    int l, ks, g, nch;
    if (h < 32) { const int s = h >> 1; l = Ls(s); ks = Kss(s); g = h & 1; nch = 5; }
    else        { l = 4; ks = h - 32; g = 0; nch = 4; }
    const u16* base = Wt + (size_t)l * WSLOT + (size_t)(ks * 10 + g * 5) * CHUNK
                         + lane * 8;
#pragma unroll
    for (int jj = 0; jj < 5; ++jj)
        if (jj < nch) buf[jj] = *(const short8*)&base[jj * CHUNK];
}

// ---- full-width epilogue: relu + packed bf16, k'-permuted swizzled store ---
__device__ __forceinline__ void epilogueF(u16* act, int ebase, int col, int quad,
                                          f32x4 (&acc)[2][10])
{
#pragma unroll
    for (int mtl = 0; mtl < 2; ++mtl)
#pragma unroll
        for (int r = 0; r < 4; ++r) {
            const int row = ebase + mtl * 16 + quad * 4 + r;
            uint2 p0, p1;
            p0.x = pk_bf16(fmaxf(acc[mtl][0][r], 0.f), fmaxf(acc[mtl][1][r], 0.f));
            p0.y = pk_bf16(fmaxf(acc[mtl][2][r], 0.f), fmaxf(acc[mtl][3][r], 0.f));
            p1.x = pk_bf16(fmaxf(acc[mtl][5][r], 0.f), fmaxf(acc[mtl][6][r], 0.f));
            p1.y = pk_bf16(fmaxf(acc[mtl][7][r], 0.f), fmaxf(acc[mtl][8][r], 0.f));
            *(uint2*)&act[aswz(row, col * 4)]      = p0;   // tiles 0-3
            *(uint2*)&act[aswz(row, 64 + col * 4)] = p1;   // tiles 5-8
            act[aswz(row, 128 + col)] =
                (u16)pk_bf16(fmaxf(acc[mtl][4][r], 0.f), 0.f);   // tile 4
            u16 sv = (u16)pk_bf16(fmaxf(acc[mtl][9][r], 0.f), 0.f);
            if (col == 6) sv = 0x3F80;                     // n=150 := 1.0 (bias)
            act[aswz(row, 144 + col)] = sv;                // tile 9
        }
}

// ====================== counting sort of edges by tgt =======================
__global__ void hist_kernel(const int* __restrict__ tgt, u32* __restrict__ cnt,
                            int n_edges)
{
    const int e = blockIdx.x * blockDim.x + threadIdx.x;
    if (e < n_edges) atomicAdd(&cnt[tgt[e]], 1u);
}

__global__ void scan1_kernel(const u32* __restrict__ cnt, u32* __restrict__ offs,
                             u32* __restrict__ bsum, int n)
{
    __shared__ u32 s[256];
    const int i = blockIdx.x * 256 + threadIdx.x;
    const u32 v = (i < n) ? cnt[i] : 0u;
    s[threadIdx.x] = v; __syncthreads();
#pragma unroll
    for (int d = 1; d < 256; d <<= 1) {
        const u32 t = (threadIdx.x >= d) ? s[threadIdx.x - d] : 0u;
        __syncthreads();
        s[threadIdx.x] += t;
        __syncthreads();
    }
    if (i < n) offs[i] = s[threadIdx.x] - v;         // exclusive within block
    if (threadIdx.x == 255) bsum[blockIdx.x] = s[255];
}

__global__ void scan2_kernel(u32* __restrict__ bsum, int nb)   // nb <= 512
{
    __shared__ u32 s[512];
    const int i = threadIdx.x;
    const u32 v = (i < nb) ? bsum[i] : 0u;
    s[i] = v; __syncthreads();
#pragma unroll
    for (int d = 1; d < 512; d <<= 1) {
        const u32 t = (i >= d) ? s[i - d] : 0u;
        __syncthreads();
        s[i] += t;
        __syncthreads();
    }
    if (i < nb) bsum[i] = s[i] - v;                  // exclusive block bases
}

__global__ void scan3_kernel(u32* __restrict__ offs, const u32* __restrict__ bsum,
                             u32* __restrict__ cursor, int n, int n_edges)
{
    const int i = blockIdx.x * 256 + threadIdx.x;
    if (i < n) {
        const u32 o = offs[i] + bsum[blockIdx.x];
        offs[i] = o;
        cursor[i] = o;
    }
    if (blockIdx.x == 0 && threadIdx.x == 0) offs[n] = (u32)n_edges;
}

__global__ void perm_kernel(const int* __restrict__ src, const int* __restrict__ tgt,
                            u32* __restrict__ cursor, int2* __restrict__ sg,
                            int n_edges)
{
    const int e = blockIdx.x * blockDim.x + threadIdx.x;
    if (e < n_edges) {
        const int g = tgt[e];
        const u32 pos = atomicAdd(&cursor[g], 1u);
        sg[pos] = make_int2(src[e], g);
    }
}

// ------------------------------- Edge kernel --------------------------------
// BARRIER-FREE (R7) + TRIPLE-BUFFERED B halves: prefetch distance 3 halves
// (~1.5 slices of compute) to cover the ~250-cyc L2 latency of B refills.
__global__ __launch_bounds__(NTHR, 3) void edge_kernel(
    const float* __restrict__ t, const float* __restrict__ x, const float* __restrict__ Ofx,
    const int2* __restrict__ sgp,
    const u16* __restrict__ Wt,
    float* __restrict__ Ep, int n_edges)
{
    __shared__ __align__(16) u16 act[BLK_E * SA];      // 49152 B, 32 rows per wave
    __shared__ int tgt_s[BLK_E];

    const int tid   = threadIdx.x;
    const int lane  = tid & 63;
    const int wv    = tid >> 6;        // 0..3
    const int ebase = wv * 32;         // this wave's 32 act rows
    const int col   = lane & 15;
    const int quad  = lane >> 4;

    // ---- gather R': this wave's 32 edges (lanes 0-31, one edge each) -------
    if (lane < 32) {
        const int e = ebase + lane;
        const long long ge = (long long)blockIdx.x * BLK_E + e;
        const bool valid = ge < n_edges;
        const int2 sg = valid ? sgp[ge] : make_int2(0, 0);
        const int g = valid ? sg.y : -1;
        const float4 xs = valid ? *(const float4*)&x[(size_t)sg.x * 4] : float4{0, 0, 0, 0};
        const float2 os = valid ? *(const float2*)&Ofx[(size_t)sg.x * 2] : float2{0, 0};
        const float4 xg = valid ? *(const float4*)&x[(size_t)sg.y * 4] : float4{0, 0, 0, 0};
        const float2 og = valid ? *(const float2*)&Ofx[(size_t)sg.y * 2] : float2{0, 0};
        const float tv = valid ? t[0] : 0.f;
        uint4 w0, w1;
        w0.x = pk_bf16(xs.x, xs.y); w0.y = pk_bf16(xs.z, xs.w);
        w0.z = pk_bf16(os.x, os.y); w0.w = pk_bf16(xg.x, xg.y);
        w1.x = pk_bf16(xg.z, xg.w); w1.y = pk_bf16(og.x, og.y);
        w1.z = pk_bf16(tv, 1.0f);   w1.w = 0u;     // k=13 := 1 (bias neuron)
        *(uint4*)&act[aswz(e, 0)]  = w0;
        *(uint4*)&act[aswz(e, 8)]  = w1;
        *(uint4*)&act[aswz(e, 16)] = uint4{0, 0, 0, 0};
        *(uint4*)&act[aswz(e, 24)] = uint4{0, 0, 0, 0};
        tgt_s[e] = g;
    }
    // no __syncthreads: same-wave DS ordering; rows are wave-private.

    const f32x4 z = {0.f, 0.f, 0.f, 0.f};
    f32x4 acc[2][10];
    short8 Wb[3][5];
    short8 Af[2];

    // prologue: prefetch halves 0,1,2 (1.5 slices deep)
    loadHalfH(Wt, 0, lane, Wb[0]);
    loadHalfH(Wt, 1, lane, Wb[1]);
    loadHalfH(Wt, 2, lane, Wb[2]);

    // ---- s=0..15: L0..L3, full N width per wave ----------------------------
#pragma unroll
    for (int s = 0; s <= 15; ++s) {
        const int ks = Kss(s);
        const bool first = (s == 0) || (ks == 0);
        const int h0 = 2 * s, h1 = 2 * s + 1;
        // A frags for this k-slice (wave-private rows)
#pragma unroll
        for (int mtl = 0; mtl < 2; ++mtl)
            Af[mtl] = *(const short8*)&act[aswz(ebase + mtl * 16 + col,
                                                ks * 32 + quad * 8)];
        // half G0: tiles 0-4 (buffer h0%3), then refill it with half h0+3
#pragma unroll
        for (int jj = 0; jj < 5; ++jj)
#pragma unroll
            for (int mtl = 0; mtl < 2; ++mtl)
                acc[mtl][jj] = __builtin_amdgcn_mfma_f32_16x16x32_bf16(
                    Af[mtl], Wb[h0 % 3][jj], first ? z : acc[mtl][jj], 0, 0, 0);
        loadHalfH(Wt, h0 + 3, lane, Wb[h0 % 3]);          // h0+3 <= 33
        // half G1: tiles 5-9 (buffer h1%3), then refill it with half h1+3
#pragma unroll
        for (int jj = 0; jj < 5; ++jj)
#pragma unroll
            for (int mtl = 0; mtl < 2; ++mtl)
                acc[mtl][5 + jj] = __builtin_amdgcn_mfma_f32_16x16x32_bf16(
                    Af[mtl], Wb[h1 % 3][jj], first ? z : acc[mtl][5 + jj], 0, 0, 0);
        loadHalfH(Wt, h1 + 3, lane, Wb[h1 % 3]);          // h1+3 <= 34
        // layer boundary: epilogue (wave-private rows; same-wave DS order)
        if (s == 0 || ks == 4)
            epilogueF(act, ebase, col, quad, acc);
    }

    // ---- L4: ks=0..4, N=50 (4 tiles), both M-tiles -------------------------
    f32x4 acc4[2][4];
#pragma unroll
    for (int ks4 = 0; ks4 < 5; ++ks4) {
        const int h = 32 + ks4;
#pragma unroll
        for (int mtl = 0; mtl < 2; ++mtl)
            Af[mtl] = *(const short8*)&act[aswz(ebase + mtl * 16 + col,
                                                ks4 * 32 + quad * 8)];
#pragma unroll
        for (int jj = 0; jj < 4; ++jj)
#pragma unroll
            for (int mtl = 0; mtl < 2; ++mtl)
                acc4[mtl][jj] = __builtin_amdgcn_mfma_f32_16x16x32_bf16(
                    Af[mtl], Wb[h % 3][jj], (ks4 == 0) ? z : acc4[mtl][jj], 0, 0, 0);
        if (h + 3 <= 36) loadHalfH(Wt, h + 3, lane, Wb[h % 3]);
    }

    // ---- wave-private E tile + run-scan scatter ----------------------------
    // f32 [32][52] overlaid on this wave's OWN act rows (6656 B < 12288 B).
    float* actF = (float*)&act[ebase * SA];
#pragma unroll
    for (int mtl = 0; mtl < 2; ++mtl)
#pragma unroll
        for (int jj = 0; jj < 4; ++jj) {
            const int n = jj * 16 + col;
            if (n < 50) {
#pragma unroll
                for (int r = 0; r < 4; ++r)
                    actF[(mtl * 16 + quad * 4 + r) * 52 + n] = acc4[mtl][jj][r];
            }
        }
    // lanes 0-49: scan this wave's 32 sorted rows, one atomic per run segment
    if (lane < 50) {
        const int c = lane;
        int   cur = tgt_s[ebase];
        float a   = 0.f;
        for (int r = 0; r < 32; ++r) {
            const int   g = tgt_s[ebase + r];
            const float v = actF[r * 52 + c];
            if (g != cur) {
                if (cur >= 0) atomicAdd(&Ep[(size_t)cur * 50 + c], a);
                a = 0.f; cur = g;
            }
            a += v;
        }
        if (cur >= 0) atomicAdd(&Ep[(size_t)cur * 50 + c], a);
    }
}

// ---------------- Node kernel: fO MLP (fp32 VALU) ---------------------------
template<int DI, int DO, bool RELU>
__device__ __forceinline__ void mlp_layer_t(
    const float* __restrict__ W, const float* __restrict__ B,
    float (*in)[64], float (*out)[64], int tid)
{
    const int et = tid & 15;
    const int jt = tid >> 4;
    constexpr int NG = (DO + 15) / 16;

    float acc0[NG], acc1[NG], acc2[NG], acc3[NG];
#pragma unroll
    for (int g = 0; g < NG; ++g) {
        const int j = jt + 16 * g;
        const float bb = (j < DO) ? B[j] : 0.f;
        acc0[g] = bb; acc1[g] = bb; acc2[g] = bb; acc3[g] = bb;
    }
    for (int k = 0; k < DI; ++k) {
        const float4 a = *(const float4*)&in[k][et * 4];
#pragma unroll
        for (int g = 0; g < NG; ++g) {
            const int j = jt + 16 * g;
            const float wv = (j < DO) ? W[k * DO + j] : 0.f;
            acc0[g] = fmaf(a.x, wv, acc0[g]);
            acc1[g] = fmaf(a.y, wv, acc1[g]);
            acc2[g] = fmaf(a.z, wv, acc2[g]);
            acc3[g] = fmaf(a.w, wv, acc3[g]);
        }
    }
#pragma unroll
    for (int g = 0; g < NG; ++g) {
        const int j = jt + 16 * g;
        if (j < DO) {
            float4 v; v.x = acc0[g]; v.y = acc1[g]; v.z = acc2[g]; v.w = acc3[g];
            if (RELU) {
                v.x = fmaxf(v.x, 0.f); v.y = fmaxf(v.y, 0.f);
                v.z = fmaxf(v.z, 0.f); v.w = fmaxf(v.w, 0.f);
            }
            *(float4*)&out[j][et * 4] = v;
        }
    }
}

__global__ __launch_bounds__(256, 2) void node_kernel(
    const float* __restrict__ Ep,
    const float* __restrict__ W0, const float* __restrict__ B0,
    const float* __restrict__ W1, const float* __restrict__ B1,
    float* __restrict__ P, int n_nodes)
{
    __shared__ float bufA[104][64];
    __shared__ float bufB[104][64];
    const int tid = threadIdx.x;
    const int n0  = blockIdx.x * 64;

    for (int idx = tid; idx < 64 * 50; idx += 256) {
        const int e = idx / 50;
        const int k = idx - e * 50;
        const int n = n0 + e;
        bufA[k][e] = (n < n_nodes) ? Ep[(size_t)n * 50 + k] : 0.f;
    }
    __syncthreads();
    mlp_layer_t<50, 100, true >(W0, B0, bufA, bufB, tid); __syncthreads();
    mlp_layer_t<100, 4, false>(W1, B1, bufB, bufA, tid); __syncthreads();
    for (int idx = tid; idx < 64 * 4; idx += 256) {
        const int e = idx & 63;
        const int j = idx >> 6;
        const int n = n0 + e;
        if (n < n_nodes) P[(size_t)n * 4 + j] = bufA[j][e];
    }
}

// ------------------------------- launcher -----------------------------------
extern "C" void kernel_launch(void* const* d_in, const int* in_sizes, int n_in,
                              void* d_out, int out_size, void* d_ws, size_t ws_size,
                              hipStream_t stream)
{
    const float* t   = (const float*)d_in[0];
    const float* x   = (const float*)d_in[1];
    const float* Ofx = (const float*)d_in[2];
    const int*   src = (const int*)d_in[3];
    const int*   tgt = (const int*)d_in[4];
    const float* W0  = (const float*)d_in[5];  const float* B0 = (const float*)d_in[6];
    const float* W1  = (const float*)d_in[7];  const float* B1 = (const float*)d_in[8];
    const float* W2  = (const float*)d_in[9];  const float* B2 = (const float*)d_in[10];
    const float* W3  = (const float*)d_in[11]; const float* B3 = (const float*)d_in[12];
    const float* W4  = (const float*)d_in[13]; const float* B4 = (const float*)d_in[14];
    const float* OW0 = (const float*)d_in[15]; const float* OB0 = (const float*)d_in[16];
    const float* OW1 = (const float*)d_in[17]; const float* OB1 = (const float*)d_in[18];

    const int n_nodes = in_sizes[1] / 4;
    const int n_edges = in_sizes[3];

    // workspace layout (all 256-B aligned)
    auto align256 = [](size_t v) { return (v + 255) & ~(size_t)255; };
    char* ws = (char*)d_ws;
    const size_t copy_elems = (size_t)n_nodes * 50;
    size_t o = 0;
    u16*   Wt       = (u16*)(ws + o);  o = WS_HDR;
    float* Ep       = (float*)(ws + o); o = align256(o + copy_elems * sizeof(float));
    u32*   offs     = (u32*)(ws + o);  o = align256(o + (size_t)(n_nodes + 1) * 4);
    u32*   cursor   = (u32*)(ws + o);  o = align256(o + (size_t)n_nodes * 4);  // also hist cnt
    u32*   bsum     = (u32*)(ws + o);  o = align256(o + 512 * 4);
    int2*  sg_perm  = (int2*)(ws + o); o = align256(o + (size_t)n_edges * 8);

    const int NB  = (n_nodes + 255) / 256;          // 391 for 100K (scan2 handles <=512)
    const int EBK = (n_edges + 255) / 256;

    prep_all<<<dim3(32, 6), 256, 0, stream>>>(W0, W1, W2, W3, W4,
                                              B0, B1, B2, B3, B4, Wt,
                                              cursor, n_nodes);
    hipMemsetAsync(Ep, 0, copy_elems * sizeof(float), stream);

    // counting sort of edges by tgt
    hist_kernel <<<EBK, 256, 0, stream>>>(tgt, cursor, n_edges);
    scan1_kernel<<<NB, 256, 0, stream>>>(cursor, offs, bsum, n_nodes);
    scan2_kernel<<<1, 512, 0, stream>>>(bsum, NB);
    scan3_kernel<<<NB, 256, 0, stream>>>(offs, bsum, cursor, n_nodes, n_edges);
    perm_kernel <<<EBK, 256, 0, stream>>>(src, tgt, cursor, sg_perm, n_edges);

    edge_kernel<<<(n_edges + BLK_E - 1) / BLK_E, NTHR, 0, stream>>>(
        t, x, Ofx, sg_perm, Wt, Ep, n_edges);

    node_kernel<<<(n_nodes + 63) / 64, 256, 0, stream>>>(
        Ep, OW0, OB0, OW1, OB1, (float*)d_out, n_nodes);
}